// Round 5
// baseline (1229.604 us; speedup 1.0000x reference)
//
#include <hip/hip_runtime.h>
#include <math.h>

typedef unsigned short u16;
typedef unsigned int u32;

using bf16x8 = __attribute__((ext_vector_type(8))) short;  // 8 bf16 (4 VGPRs)
using f32x4  = __attribute__((ext_vector_type(4))) float;  // 4 fp32 acc

__device__ __forceinline__ u16 f2bf(float f) {
  u32 u = __float_as_uint(f);
  u32 r = u + 0x7FFFu + ((u >> 16) & 1u);   // RNE
  return (u16)(r >> 16);
}
__device__ __forceinline__ float bf2f(u16 h) {
  return __uint_as_float(((u32)h) << 16);
}

// async global->LDS, 16B per lane; lds ptr must be wave-uniform base (HW adds lane*16)
__device__ __forceinline__ void gll16(const u16* g, u16* l) {
  __builtin_amdgcn_global_load_lds((const __attribute__((address_space(1))) void*)g,
                                   (__attribute__((address_space(3))) void*)l, 16, 0, 0);
}

// ---------------- fp32 -> bf16 cast (weights) ----------------
__global__ __launch_bounds__(256) void k_split(const float* __restrict__ src,
                                               u16* __restrict__ h) {
  size_t i = ((size_t)blockIdx.x << 8) + threadIdx.x;
  float4 v = *(const float4*)(src + (i << 2));
  ushort4 hv;
  hv.x = f2bf(v.x);
  hv.y = f2bf(v.y);
  hv.z = f2bf(v.z);
  hv.w = f2bf(v.w);
  *(ushort4*)(h + (i << 2)) = hv;
}

// ------- build 8 pre-shifted reversed-w copies: wr8[p][i] = bf16(w[4095-(i+p)]), 0 if i+p>4095 -------
__global__ __launch_bounds__(256) void k_wsplit(const float* __restrict__ w,
                                                u16* __restrict__ wrh8) {
  int bid = blockIdx.x;                 // 8 * 17 = 136 blocks
  int p = bid / 17;
  int i = (bid % 17) * 256 + threadIdx.x;   // [0, 4352)
  int j = i + p;
  float v = (j <= 4095) ? w[4095 - j] : 0.0f;
  wrh8[(size_t)p * 4352 + i] = f2bf(v);
}

// ------- transpose: x [4][4096][1024] f32 -> Xth [4][1024][4096] bf16 -------
__global__ __launch_bounds__(256) void k_tsplit(const float* __restrict__ x,
                                                u16* __restrict__ Xth) {
  __shared__ float tile[64 * 65];
  int bid = blockIdx.x;
  int b = bid >> 10; int rem = bid & 1023;
  int mt = rem >> 4; int dt = rem & 15;
  int m0 = mt << 6, d0 = dt << 6;
  int tid = threadIdx.x;
  int rr = tid >> 4, cc = (tid & 15) << 2;
#pragma unroll
  for (int i = 0; i < 4; i++) {
    int r = (i << 4) + rr;   // m-row within tile
    float4 v = *(const float4*)(x + (size_t)(b * 4096 + m0 + r) * 1024 + d0 + cc);
    tile[r * 65 + cc + 0] = v.x; tile[r * 65 + cc + 1] = v.y;
    tile[r * 65 + cc + 2] = v.z; tile[r * 65 + cc + 3] = v.w;
  }
  __syncthreads();
#pragma unroll
  for (int i = 0; i < 4; i++) {
    int rd = (i << 4) + rr;  // d-row within tile
    ushort4 hv;
    hv.x = f2bf(tile[(cc + 0) * 65 + rd]);
    hv.y = f2bf(tile[(cc + 1) * 65 + rd]);
    hv.z = f2bf(tile[(cc + 2) * 65 + rd]);
    hv.w = f2bf(tile[(cc + 3) * 65 + rd]);
    size_t o = (size_t)(b * 1024 + d0 + rd) * 4096 + m0 + cc;
    *(ushort4*)(Xth + o) = hv;
  }
}

// ------- conv MFMA: U[b,n,d] = x + (sum_{m<=n} w[n-m] x[b,m,d]) * rsqrt(n+1) -------
// LDS layout: k-quad-major [4][128][8] (conflict-free ds_read_b128).
__global__ __launch_bounds__(256) void k_convm(const u16* __restrict__ Xth,
                                               const u16* __restrict__ wrh8,
                                               const float* __restrict__ x,
                                               float* __restrict__ U) {
  __shared__ __align__(16) u16 smem[8192];
  u16* Ash = smem;            // [4][128][8]
  u16* Bsh = smem + 4096;     // [4][128][8]
  int bid = blockIdx.x;
  int nt = 31 - (bid >> 5);        // descending: heavy blocks launch first
  int b  = (bid >> 3) & 3;
  int dt = bid & 7;
  int n0 = nt << 7, d0 = dt << 7;
  int tid = threadIdx.x, lane = tid & 63, w4 = tid >> 6;
  int wm = w4 >> 1, wn = w4 & 1;
  const u16* Xbh = Xth + (size_t)b * 4194304;
  f32x4 acc[4][4];
#pragma unroll
  for (int i = 0; i < 4; i++)
#pragma unroll
    for (int j = 0; j < 4; j++) { acc[i][j][0] = 0.f; acc[i][j][1] = 0.f; acc[i][j][2] = 0.f; acc[i][j][3] = 0.f; }
  int arow0 = (wm << 6) + (lane & 15);
  int brow0 = (wn << 6) + (lane & 15);
  int koff = (lane >> 4) << 10;         // kq subtile base in u16
  int kIters = (nt << 2) + 4;           // m in [0, n0+128)
  for (int it = 0; it < kIters; ++it) {
    int m0 = it << 5;
    int C = 4095 - n0 + m0;             // A row r k-run starts at wrev[C - r]
#pragma unroll
    for (int c = 0; c < 2; ++c) {
      int s = (c << 8) + tid;
      int r = s & 127, kq = s >> 7;
      int lb = (s & ~63) << 3;          // wave-uniform u16 offset (dest = lb + lane*8)
      int base = C - r;
      int p = base & 7;
      size_t ao = (size_t)p * 4352 + (base - p) + (kq << 3);   // 16B-aligned
      gll16(wrh8 + ao, Ash + lb);
      size_t go = (size_t)(d0 + r) * 4096 + m0 + (kq << 3);
      gll16(Xbh + go, Bsh + lb);
    }
    __syncthreads();
    bf16x8 af[4], bfh[4];
#pragma unroll
    for (int i = 0; i < 4; i++)
      af[i] = *(const bf16x8*)(Ash + koff + ((arow0 + (i << 4)) << 3));
#pragma unroll
    for (int j = 0; j < 4; j++)
      bfh[j] = *(const bf16x8*)(Bsh + koff + ((brow0 + (j << 4)) << 3));
#pragma unroll
    for (int i = 0; i < 4; i++)
#pragma unroll
      for (int j = 0; j < 4; j++)
        acc[i][j] = __builtin_amdgcn_mfma_f32_16x16x32_bf16(af[i], bfh[j], acc[i][j], 0, 0, 0);
    __syncthreads();
  }
  // epilogue: U[n][d] = x[n][d] + acc * rsqrt(n+1)  (fp32, 64B-sector aligned -- keep direct)
#pragma unroll
  for (int i = 0; i < 4; i++) {
    int nb_ = n0 + (wm << 6) + (i << 4) + ((lane >> 4) << 2);
#pragma unroll
    for (int q = 0; q < 4; q++) {
      int n = nb_ + q;
      float scale = rsqrtf((float)(n + 1));
#pragma unroll
      for (int j = 0; j < 4; j++) {
        int d = d0 + (wn << 6) + (j << 4) + (lane & 15);
        size_t idx = ((size_t)(b * 4096 + n)) * 1024 + d;
        U[idx] = x[idx] + acc[i][j][q] * scale;
      }
    }
  }
}

// ---------------- block reduction over 256 threads (4 waves) ----------------
__device__ __forceinline__ float blk_sum(float v, float* sb, int tid) {
#pragma unroll
  for (int off = 32; off > 0; off >>= 1) v += __shfl_down(v, off, 64);
  int wid = tid >> 6;
  if ((tid & 63) == 0) sb[wid] = v;
  __syncthreads();
  if (tid == 0) sb[4] = sb[0] + sb[1] + sb[2] + sb[3];
  __syncthreads();
  return sb[4];
}

// ---------------- LN1: X1 = LN(U; g,b), emitted as bf16 hi/lo pair ----------------
__global__ __launch_bounds__(256) void k_ln1b(const float* __restrict__ U,
                                              const float* __restrict__ g,
                                              const float* __restrict__ bt,
                                              u16* __restrict__ X1h,
                                              u16* __restrict__ X1l) {
  __shared__ float sb[8];
  int row = blockIdx.x; int tid = threadIdx.x;
  int c = tid << 2;
  float4 v = *(const float4*)(U + (size_t)row * 1024 + c);
  float mu = blk_sum(v.x + v.y + v.z + v.w, sb, tid) * (1.0f / 1024.0f);
  float dx = v.x - mu, dy = v.y - mu, dz = v.z - mu, dw = v.w - mu;
  float var = blk_sum(dx * dx + dy * dy + dz * dz + dw * dw, sb, tid) * (1.0f / 1024.0f);
  float rs = 1.0f / sqrtf(var + 1e-5f);
  float4 gv = *(const float4*)(g + c);
  float4 bv = *(const float4*)(bt + c);
  float o0 = dx * rs * gv.x + bv.x;
  float o1 = dy * rs * gv.y + bv.y;
  float o2 = dz * rs * gv.z + bv.z;
  float o3 = dw * rs * gv.w + bv.w;
  ushort4 hv, lv;
  hv.x = f2bf(o0); lv.x = f2bf(o0 - bf2f(hv.x));
  hv.y = f2bf(o1); lv.y = f2bf(o1 - bf2f(hv.y));
  hv.z = f2bf(o2); lv.z = f2bf(o2 - bf2f(hv.z));
  hv.w = f2bf(o3); lv.w = f2bf(o3 - bf2f(hv.w));
  *(ushort4*)(X1h + (size_t)row * 1024 + c) = hv;
  *(ushort4*)(X1l + (size_t)row * 1024 + c) = lv;
}

// ------- FFN1 MFMA: Hc = gelu(X1 @ w1^T + b1), pure bf16, one expert per call -------
// k-major LDS staging; LDS-staged coalesced bf16 output (2 passes of 64 rows).
__global__ __launch_bounds__(256) void k_ffn1m(const u16* __restrict__ X1h,
                                               const u16* __restrict__ W1h,
                                               const float* __restrict__ b1a, const float* __restrict__ b1b,
                                               u16* __restrict__ Hch, int e) {
  __shared__ __align__(16) u16 smem[8448];   // staging 2x4096; epilogue 64x132
  u16* Ash = smem;
  u16* Bsh = smem + 4096;
  int bid = blockIdx.x;
  int mt = bid >> 5, ct = bid & 31;           // mt 0..63, ct 0..31
  int chunk = mt >> 4, rloc = mt & 15;
  size_t arow0g = (size_t)chunk * 4096 + (size_t)e * 2048 + (size_t)rloc * 128;
  int hrow0 = mt << 7;
  const u16* Bh = W1h + (size_t)e * 4194304;
  const float* b1 = e ? b1b : b1a;
  int tid = threadIdx.x, lane = tid & 63, w = tid >> 6;
  int wm = w >> 1, wn = w & 1;
  int col0 = ct << 7;
  f32x4 acc[4][4];
#pragma unroll
  for (int i = 0; i < 4; i++)
#pragma unroll
    for (int j = 0; j < 4; j++) { acc[i][j][0] = 0.f; acc[i][j][1] = 0.f; acc[i][j][2] = 0.f; acc[i][j][3] = 0.f; }
  int arow0 = (wm << 6) + (lane & 15);
  int brow0 = (wn << 6) + (lane & 15);
  int koff = (lane >> 4) << 10;
  for (int kt = 0; kt < 32; ++kt) {
    int k0 = kt << 5;
#pragma unroll
    for (int c = 0; c < 2; ++c) {
      int s = (c << 8) + tid;
      int r = s & 127, kq = s >> 7;
      int lb = (s & ~63) << 3;
      gll16(X1h + (arow0g + r) * 1024 + k0 + (kq << 3), Ash + lb);
      gll16(Bh + (size_t)(col0 + r) * 1024 + k0 + (kq << 3), Bsh + lb);
    }
    __syncthreads();
    bf16x8 af[4], bfh[4];
#pragma unroll
    for (int i = 0; i < 4; i++)
      af[i] = *(const bf16x8*)(Ash + koff + ((arow0 + (i << 4)) << 3));
#pragma unroll
    for (int j = 0; j < 4; j++)
      bfh[j] = *(const bf16x8*)(Bsh + koff + ((brow0 + (j << 4)) << 3));
#pragma unroll
    for (int i = 0; i < 4; i++)
#pragma unroll
      for (int j = 0; j < 4; j++)
        acc[i][j] = __builtin_amdgcn_mfma_f32_16x16x32_bf16(af[i], bfh[j], acc[i][j], 0, 0, 0);
    __syncthreads();
  }
  // epilogue: bias + exact gelu, LDS-staged coalesced bf16 stores
#pragma unroll
  for (int p = 0; p < 2; ++p) {
    if (wm == p) {
#pragma unroll
      for (int j = 0; j < 4; j++) {
        int fl = (wn << 6) + (j << 4) + (lane & 15);     // local col 0..127
        float bv = b1[col0 + fl];
#pragma unroll
        for (int i = 0; i < 4; i++) {
          int rl = (i << 4) + ((lane >> 4) << 2);        // local row 0..60
#pragma unroll
          for (int q = 0; q < 4; q++) {
            float v = acc[i][j][q] + bv;
            float ge = 0.5f * v * (1.0f + erff(v * 0.70710678118654752f));
            smem[(rl + q) * 132 + fl] = f2bf(ge);
          }
        }
      }
    }
    __syncthreads();
#pragma unroll
    for (int v = 0; v < 4; v++) {
      int idx = (v << 8) + tid;          // 0..1023
      int row = idx >> 4, cq = idx & 15;
      bf16x8 val = *(const bf16x8*)(smem + row * 132 + (cq << 3));
      *(bf16x8*)(Hch + (size_t)(hrow0 + (p << 6) + row) * 4096 + col0 + (cq << 3)) = val;
    }
    __syncthreads();
  }
}

// ------- FFN2 MFMA: Y = Hc @ w2^T, pure bf16, 128x128 tile, 4 waves, one expert -------
__global__ __launch_bounds__(256) void k_ffn2m(const u16* __restrict__ Hch,
                                               const u16* __restrict__ W2h,
                                               u16* __restrict__ Yb, int e) {
  __shared__ __align__(16) u16 smem[8448];
  u16* Ash = smem;
  u16* Bsh = smem + 4096;
  int bid = blockIdx.x;
  int mt = bid >> 3, ct = bid & 7;            // mt 0..63, ct 0..7
  int chunk = mt >> 4, rloc = mt & 15;
  int arow0h = mt << 7;                       // Hc linear row
  size_t yrow0g = (size_t)chunk * 4096 + (size_t)e * 2048 + (size_t)rloc * 128;
  const u16* Bh = W2h + (size_t)e * 4194304;
  int tid = threadIdx.x, lane = tid & 63, w = tid >> 6;
  int wm = w >> 1, wn = w & 1;
  int col0 = ct << 7;
  f32x4 acc[4][4];
#pragma unroll
  for (int i = 0; i < 4; i++)
#pragma unroll
    for (int j = 0; j < 4; j++) { acc[i][j][0] = 0.f; acc[i][j][1] = 0.f; acc[i][j][2] = 0.f; acc[i][j][3] = 0.f; }
  int arow0 = (wm << 6) + (lane & 15);
  int brow0 = (wn << 6) + (lane & 15);
  int koff = (lane >> 4) << 10;
  for (int kt = 0; kt < 128; ++kt) {
    int k0 = kt << 5;
#pragma unroll
    for (int c = 0; c < 2; ++c) {
      int s = (c << 8) + tid;
      int r = s & 127, kq = s >> 7;
      int lb = (s & ~63) << 3;
      gll16(Hch + (size_t)(arow0h + r) * 4096 + k0 + (kq << 3), Ash + lb);
      gll16(Bh + (size_t)(col0 + r) * 4096 + k0 + (kq << 3), Bsh + lb);
    }
    __syncthreads();
    bf16x8 af[4], bfh[4];
#pragma unroll
    for (int i = 0; i < 4; i++)
      af[i] = *(const bf16x8*)(Ash + koff + ((arow0 + (i << 4)) << 3));
#pragma unroll
    for (int j = 0; j < 4; j++)
      bfh[j] = *(const bf16x8*)(Bsh + koff + ((brow0 + (j << 4)) << 3));
#pragma unroll
    for (int i = 0; i < 4; i++)
#pragma unroll
      for (int j = 0; j < 4; j++)
        acc[i][j] = __builtin_amdgcn_mfma_f32_16x16x32_bf16(af[i], bfh[j], acc[i][j], 0, 0, 0);
    __syncthreads();
  }
  // epilogue: LDS-staged coalesced bf16 stores
#pragma unroll
  for (int p = 0; p < 2; ++p) {
    if (wm == p) {
#pragma unroll
      for (int j = 0; j < 4; j++) {
        int fl = (wn << 6) + (j << 4) + (lane & 15);
#pragma unroll
        for (int i = 0; i < 4; i++) {
          int rl = (i << 4) + ((lane >> 4) << 2);
#pragma unroll
          for (int q = 0; q < 4; q++)
            smem[(rl + q) * 132 + fl] = f2bf(acc[i][j][q]);
        }
      }
    }
    __syncthreads();
#pragma unroll
    for (int v = 0; v < 4; v++) {
      int idx = (v << 8) + tid;
      int row = idx >> 4, cq = idx & 15;
      bf16x8 val = *(const bf16x8*)(smem + row * 132 + (cq << 3));
      *(bf16x8*)(Yb + (yrow0g + (p << 6) + row) * 1024 + col0 + (cq << 3)) = val;
    }
    __syncthreads();
  }
}

// ------- LN2: out = LN((X1h+X1l) + s*(Y + b2); lng,lnb) -- fp32 out -------
__global__ __launch_bounds__(256) void k_ln2b(const u16* __restrict__ Yb,
                                              const u16* __restrict__ X1h, const u16* __restrict__ X1l,
                                              const float* __restrict__ b2a, const float* __restrict__ b2b,
                                              const float* __restrict__ sa, const float* __restrict__ sbp,
                                              const float* __restrict__ ga, const float* __restrict__ gb,
                                              const float* __restrict__ ba, const float* __restrict__ bbp,
                                              float* __restrict__ out) {
  __shared__ float sb[8];
  int row = blockIdx.x; int tid = threadIdx.x;
  int n = row & 4095; int e = n >> 11;
  const float* b2 = e ? b2b : b2a;
  const float* lg = e ? gb : ga;
  const float* lb = e ? bbp : ba;
  float s = e ? sbp[0] : sa[0];
  int c = tid << 2;
  ushort4 yv = *(const ushort4*)(Yb + (size_t)row * 1024 + c);
  ushort4 hv = *(const ushort4*)(X1h + (size_t)row * 1024 + c);
  ushort4 lv = *(const ushort4*)(X1l + (size_t)row * 1024 + c);
  float4 b2v = *(const float4*)(b2 + c);
  float x0 = bf2f(hv.x) + bf2f(lv.x);
  float x1 = bf2f(hv.y) + bf2f(lv.y);
  float x2 = bf2f(hv.z) + bf2f(lv.z);
  float x3 = bf2f(hv.w) + bf2f(lv.w);
  float t0 = x0 + s * (bf2f(yv.x) + b2v.x);
  float t1 = x1 + s * (bf2f(yv.y) + b2v.y);
  float t2 = x2 + s * (bf2f(yv.z) + b2v.z);
  float t3 = x3 + s * (bf2f(yv.w) + b2v.w);
  float mu = blk_sum(t0 + t1 + t2 + t3, sb, tid) * (1.0f / 1024.0f);
  float d0 = t0 - mu, d1 = t1 - mu, d2 = t2 - mu, d3 = t3 - mu;
  float var = blk_sum(d0 * d0 + d1 * d1 + d2 * d2 + d3 * d3, sb, tid) * (1.0f / 1024.0f);
  float rs = 1.0f / sqrtf(var + 1e-5f);
  float4 gv = *(const float4*)(lg + c);
  float4 bv = *(const float4*)(lb + c);
  float4 o;
  o.x = d0 * rs * gv.x + bv.x;
  o.y = d1 * rs * gv.y + bv.y;
  o.z = d2 * rs * gv.z + bv.z;
  o.w = d3 * rs * gv.w + bv.w;
  *(float4*)(out + (size_t)row * 1024 + c) = o;
}

extern "C" void kernel_launch(void* const* d_in, const int* in_sizes, int n_in,
                              void* d_out, int out_size, void* d_ws, size_t ws_size,
                              hipStream_t stream) {
  (void)out_size; (void)ws_size;
  static const int SIG[18] = {16777216, 4096, 1024, 1024,
                              4194304, 4096, 4194304, 1024, 1, 1024, 1024,
                              4194304, 4096, 4194304, 1024, 1, 1024, 1024};
  const void* P[18];
  bool exact = (n_in >= 18);
  if (exact) {
    for (int i = 0; i < 18; i++) {
      if (in_sizes[i] != SIG[i]) { exact = false; break; }
    }
  }
  if (exact) {
    for (int i = 0; i < 18; i++) P[i] = d_in[i];
  } else {
    bool used[64] = {false};
    int cap = (n_in < 64) ? n_in : 64;
    for (int r = 0; r < 18; r++) {
      int found = -1;
      for (int j = 0; j < cap; j++) {
        if (!used[j] && in_sizes[j] == SIG[r]) { found = j; break; }
      }
      if (found >= 0) { used[found] = true; P[r] = d_in[found]; }
      else            { P[r] = d_in[(r < n_in) ? r : 0]; }
    }
  }
  const float* x     = (const float*)P[0];
  const float* wv    = (const float*)P[1];
  const float* ng    = (const float*)P[2];
  const float* nb    = (const float*)P[3];
  const float* w1_0  = (const float*)P[4];
  const float* b1_0  = (const float*)P[5];
  const float* w2_0  = (const float*)P[6];
  const float* b2_0  = (const float*)P[7];
  const float* s_0   = (const float*)P[8];
  const float* lng_0 = (const float*)P[9];
  const float* lnb_0 = (const float*)P[10];
  const float* w1_1  = (const float*)P[11];
  const float* b1_1  = (const float*)P[12];
  const float* w2_1  = (const float*)P[13];
  const float* b2_1  = (const float*)P[14];
  const float* s_1   = (const float*)P[15];
  const float* lng_1 = (const float*)P[16];
  const float* lnb_1 = (const float*)P[17];

  char* ws = (char*)d_ws;
  u16* W1h = (u16*)(ws + 0);           // 16 MB: [2 experts][4096][1024] bf16
  u16* W2h = (u16*)(ws + 16777216);    // 16 MB: [2 experts][1024][4096] bf16
  u16* Xth = (u16*)(ws + 33554432);    // 32 MB [4][1024][4096]  (dead after conv -> X1h)
  u16* X1h = Xth;
  u16* X1l = (u16*)(ws + 67108864);    // 32 MB [16384][1024]
  float* U = (float*)(ws + 100663296); // 64 MB fp32 conv out (dead after LN1)
  u16* Hch = (u16*)(ws + 100663296);   // 64 MB [8192][4096] bf16 (overlays U)
  u16* Yb  = (u16*)(ws + 167772160);   // 32 MB [16384][1024]
  u16* wrh8 = (u16*)(ws + 201326592);  // 8*4352*2 = 69632 B

  k_wsplit<<<136, 256, 0, stream>>>(wv, wrh8);
  k_tsplit<<<4096, 256, 0, stream>>>(x, Xth);
  k_split<<<4096, 256, 0, stream>>>(w1_0, W1h);
  k_split<<<4096, 256, 0, stream>>>(w1_1, W1h + 4194304);
  k_split<<<4096, 256, 0, stream>>>(w2_0, W2h);
  k_split<<<4096, 256, 0, stream>>>(w2_1, W2h + 4194304);
  k_convm<<<1024, 256, 0, stream>>>(Xth, wrh8, x, U);
  k_ln1b<<<16384, 256, 0, stream>>>(U, ng, nb, X1h, X1l);
  for (int e = 0; e < 2; e++) {
    k_ffn1m<<<2048, 256, 0, stream>>>(X1h, W1h, b1_0, b1_1, Hch, e);
    k_ffn2m<<<512, 256, 0, stream>>>(Hch, W2h, Yb, e);
  }
  k_ln2b<<<16384, 256, 0, stream>>>(Yb, X1h, X1l, b2_0, b2_1, s_0, s_1,
                                    lng_0, lng_1, lnb_0, lnb_1, (float*)d_out);
}

// Round 6
// 1003.697 us; speedup vs baseline: 1.2251x; 1.2251x over previous
//
#include <hip/hip_runtime.h>
#include <math.h>

typedef unsigned short u16;
typedef unsigned int u32;

using bf16x8 = __attribute__((ext_vector_type(8))) short;  // 8 bf16 (4 VGPRs)
using f32x4  = __attribute__((ext_vector_type(4))) float;  // 4 fp32 acc

__device__ __forceinline__ u16 f2bf(float f) {
  u32 u = __float_as_uint(f);
  u32 r = u + 0x7FFFu + ((u >> 16) & 1u);   // RNE
  return (u16)(r >> 16);
}
__device__ __forceinline__ float bf2f(u16 h) {
  return __uint_as_float(((u32)h) << 16);
}

// async global->LDS, 16B per lane; lds ptr must be wave-uniform base (HW adds lane*16)
__device__ __forceinline__ void gll16(const u16* g, u16* l) {
  __builtin_amdgcn_global_load_lds((const __attribute__((address_space(1))) void*)g,
                                   (__attribute__((address_space(3))) void*)l, 16, 0, 0);
}

// counted-vmcnt barrier: wait until <=N vmem ops outstanding, then barrier.
// Single asm with memory clobber so no LDS read / gll16 crosses it.
#define PIPE_BARRIER_VM4()  asm volatile("s_waitcnt vmcnt(4)\n\ts_barrier" ::: "memory")
#define PIPE_BARRIER_VM0()  asm volatile("s_waitcnt vmcnt(0)\n\ts_barrier" ::: "memory")
#define PIPE_BARRIER_LGKM() asm volatile("s_waitcnt lgkmcnt(0)\n\ts_barrier" ::: "memory")

// ---------------- fp32 -> bf16 cast (weights) ----------------
__global__ __launch_bounds__(256) void k_split(const float* __restrict__ src,
                                               u16* __restrict__ h) {
  size_t i = ((size_t)blockIdx.x << 8) + threadIdx.x;
  float4 v = *(const float4*)(src + (i << 2));
  ushort4 hv;
  hv.x = f2bf(v.x);
  hv.y = f2bf(v.y);
  hv.z = f2bf(v.z);
  hv.w = f2bf(v.w);
  *(ushort4*)(h + (i << 2)) = hv;
}

// ------- build 8 pre-shifted reversed-w copies: wr8[p][i] = bf16(w[4095-(i+p)]), 0 if i+p>4095 -------
__global__ __launch_bounds__(256) void k_wsplit(const float* __restrict__ w,
                                                u16* __restrict__ wrh8) {
  int bid = blockIdx.x;                 // 8 * 17 = 136 blocks
  int p = bid / 17;
  int i = (bid % 17) * 256 + threadIdx.x;   // [0, 4352)
  int j = i + p;
  float v = (j <= 4095) ? w[4095 - j] : 0.0f;
  wrh8[(size_t)p * 4352 + i] = f2bf(v);
}

// ------- transpose: x [4][4096][1024] f32 -> Xth [4][1024][4096] bf16 -------
__global__ __launch_bounds__(256) void k_tsplit(const float* __restrict__ x,
                                                u16* __restrict__ Xth) {
  __shared__ float tile[64 * 65];
  int bid = blockIdx.x;
  int b = bid >> 10; int rem = bid & 1023;
  int mt = rem >> 4; int dt = rem & 15;
  int m0 = mt << 6, d0 = dt << 6;
  int tid = threadIdx.x;
  int rr = tid >> 4, cc = (tid & 15) << 2;
#pragma unroll
  for (int i = 0; i < 4; i++) {
    int r = (i << 4) + rr;   // m-row within tile
    float4 v = *(const float4*)(x + (size_t)(b * 4096 + m0 + r) * 1024 + d0 + cc);
    tile[r * 65 + cc + 0] = v.x; tile[r * 65 + cc + 1] = v.y;
    tile[r * 65 + cc + 2] = v.z; tile[r * 65 + cc + 3] = v.w;
  }
  __syncthreads();
#pragma unroll
  for (int i = 0; i < 4; i++) {
    int rd = (i << 4) + rr;  // d-row within tile
    ushort4 hv;
    hv.x = f2bf(tile[(cc + 0) * 65 + rd]);
    hv.y = f2bf(tile[(cc + 1) * 65 + rd]);
    hv.z = f2bf(tile[(cc + 2) * 65 + rd]);
    hv.w = f2bf(tile[(cc + 3) * 65 + rd]);
    size_t o = (size_t)(b * 1024 + d0 + rd) * 4096 + m0 + cc;
    *(ushort4*)(Xth + o) = hv;
  }
}

// ------- conv MFMA: U[b,n,d] = x + (sum_{m<=n} w[n-m] x[b,m,d]) * rsqrt(n+1) -------
// k-quad-major LDS [4][128][8], double-buffered, counted-vmcnt 2-phase pipeline.
__global__ __launch_bounds__(256) void k_convm(const u16* __restrict__ Xth,
                                               const u16* __restrict__ wrh8,
                                               const float* __restrict__ x,
                                               float* __restrict__ U) {
  __shared__ __align__(16) u16 smem[16384];   // 2 bufs x (A 4096 + B 4096)
  int bid = blockIdx.x;
  int nt = 31 - (bid >> 5);        // descending: heavy blocks launch first
  int b  = (bid >> 3) & 3;
  int dt = bid & 7;
  int n0 = nt << 7, d0 = dt << 7;
  int tid = threadIdx.x, lane = tid & 63, w4 = tid >> 6;
  int wm = w4 >> 1, wn = w4 & 1;
  const u16* Xbh = Xth + (size_t)b * 4194304;
  f32x4 acc[4][4];
#pragma unroll
  for (int i = 0; i < 4; i++)
#pragma unroll
    for (int j = 0; j < 4; j++) { acc[i][j][0] = 0.f; acc[i][j][1] = 0.f; acc[i][j][2] = 0.f; acc[i][j][3] = 0.f; }
  int arow0 = (wm << 6) + (lane & 15);
  int brow0 = (wn << 6) + (lane & 15);
  int koff = (lane >> 4) << 10;         // kq subtile base in u16
  int kIters = (nt << 2) + 4;           // m in [0, n0+128)

  auto STAGE = [&](int it, int bufo) {
    int m0 = it << 5;
    int C = 4095 - n0 + m0;             // A row r k-run starts at wrev[C - r]
#pragma unroll
    for (int c = 0; c < 2; ++c) {
      int s = (c << 8) + tid;
      int r = s & 127, kq = s >> 7;
      int lb = (s & ~63) << 3;          // wave-uniform u16 offset (dest = lb + lane*8)
      int base = C - r;
      int p = base & 7;
      size_t ao = (size_t)p * 4352 + (base - p) + (kq << 3);   // 16B-aligned
      gll16(wrh8 + ao, smem + bufo + lb);
      size_t go = (size_t)(d0 + r) * 4096 + m0 + (kq << 3);
      gll16(Xbh + go, smem + bufo + 4096 + lb);
    }
  };

  STAGE(0, 0);
  int cur = 0;
#pragma unroll 1
  for (int it = 0; it < kIters; ++it) {
    int nb = (cur ^ 1) << 13;
    if (it + 1 < kIters) { STAGE(it + 1, nb); PIPE_BARRIER_VM4(); }
    else                 { PIPE_BARRIER_VM0(); }
    const u16* Ab = smem + (cur << 13);
    const u16* Bb = Ab + 4096;
    bf16x8 af[4], bfh[4];
#pragma unroll
    for (int i = 0; i < 4; i++)
      af[i] = *(const bf16x8*)(Ab + koff + ((arow0 + (i << 4)) << 3));
#pragma unroll
    for (int j = 0; j < 4; j++)
      bfh[j] = *(const bf16x8*)(Bb + koff + ((brow0 + (j << 4)) << 3));
#pragma unroll
    for (int i = 0; i < 4; i++)
#pragma unroll
      for (int j = 0; j < 4; j++)
        acc[i][j] = __builtin_amdgcn_mfma_f32_16x16x32_bf16(af[i], bfh[j], acc[i][j], 0, 0, 0);
    PIPE_BARRIER_LGKM();
    cur ^= 1;
  }
  // epilogue: U[n][d] = x[n][d] + acc * rsqrt(n+1)  (fp32, sector-aligned -- direct)
#pragma unroll
  for (int i = 0; i < 4; i++) {
    int nb_ = n0 + (wm << 6) + (i << 4) + ((lane >> 4) << 2);
#pragma unroll
    for (int q = 0; q < 4; q++) {
      int n = nb_ + q;
      float scale = rsqrtf((float)(n + 1));
#pragma unroll
      for (int j = 0; j < 4; j++) {
        int d = d0 + (wn << 6) + (j << 4) + (lane & 15);
        size_t idx = ((size_t)(b * 4096 + n)) * 1024 + d;
        U[idx] = x[idx] + acc[i][j][q] * scale;
      }
    }
  }
}

// ---------------- block reduction over 256 threads (4 waves) ----------------
__device__ __forceinline__ float blk_sum(float v, float* sb, int tid) {
#pragma unroll
  for (int off = 32; off > 0; off >>= 1) v += __shfl_down(v, off, 64);
  int wid = tid >> 6;
  if ((tid & 63) == 0) sb[wid] = v;
  __syncthreads();
  if (tid == 0) sb[4] = sb[0] + sb[1] + sb[2] + sb[3];
  __syncthreads();
  return sb[4];
}

// ---------------- LN1: X1 = LN(U; g,b), emitted as bf16 hi/lo pair ----------------
__global__ __launch_bounds__(256) void k_ln1b(const float* __restrict__ U,
                                              const float* __restrict__ g,
                                              const float* __restrict__ bt,
                                              u16* __restrict__ X1h,
                                              u16* __restrict__ X1l) {
  __shared__ float sb[8];
  int row = blockIdx.x; int tid = threadIdx.x;
  int c = tid << 2;
  float4 v = *(const float4*)(U + (size_t)row * 1024 + c);
  float mu = blk_sum(v.x + v.y + v.z + v.w, sb, tid) * (1.0f / 1024.0f);
  float dx = v.x - mu, dy = v.y - mu, dz = v.z - mu, dw = v.w - mu;
  float var = blk_sum(dx * dx + dy * dy + dz * dz + dw * dw, sb, tid) * (1.0f / 1024.0f);
  float rs = 1.0f / sqrtf(var + 1e-5f);
  float4 gv = *(const float4*)(g + c);
  float4 bv = *(const float4*)(bt + c);
  float o0 = dx * rs * gv.x + bv.x;
  float o1 = dy * rs * gv.y + bv.y;
  float o2 = dz * rs * gv.z + bv.z;
  float o3 = dw * rs * gv.w + bv.w;
  ushort4 hv, lv;
  hv.x = f2bf(o0); lv.x = f2bf(o0 - bf2f(hv.x));
  hv.y = f2bf(o1); lv.y = f2bf(o1 - bf2f(hv.y));
  hv.z = f2bf(o2); lv.z = f2bf(o2 - bf2f(hv.z));
  hv.w = f2bf(o3); lv.w = f2bf(o3 - bf2f(hv.w));
  *(ushort4*)(X1h + (size_t)row * 1024 + c) = hv;
  *(ushort4*)(X1l + (size_t)row * 1024 + c) = lv;
}

// ------- FFN1 MFMA: Hc = gelu(X1 @ w1^T + b1), pure bf16, one expert per call -------
// 2-phase pipeline + XCD swizzle (same-mt blocks share bid%8 -> same XCD L2 for A panels).
__global__ __launch_bounds__(256) void k_ffn1m(const u16* __restrict__ X1h,
                                               const u16* __restrict__ W1h,
                                               const float* __restrict__ b1a, const float* __restrict__ b1b,
                                               u16* __restrict__ Hch, int e) {
  __shared__ __align__(16) u16 smem[16384];
  int bid = blockIdx.x;                           // 2048
  int mt = ((bid >> 8) << 3) | (bid & 7);         // 0..63
  int ct = (bid >> 3) & 31;                       // 0..31
  int chunk = mt >> 4, rloc = mt & 15;
  size_t arow0g = (size_t)chunk * 4096 + (size_t)e * 2048 + (size_t)rloc * 128;
  int hrow0 = mt << 7;
  const u16* Bh = W1h + (size_t)e * 4194304;
  const float* b1 = e ? b1b : b1a;
  int tid = threadIdx.x, lane = tid & 63, w = tid >> 6;
  int wm = w >> 1, wn = w & 1;
  int col0 = ct << 7;
  f32x4 acc[4][4];
#pragma unroll
  for (int i = 0; i < 4; i++)
#pragma unroll
    for (int j = 0; j < 4; j++) { acc[i][j][0] = 0.f; acc[i][j][1] = 0.f; acc[i][j][2] = 0.f; acc[i][j][3] = 0.f; }
  int arow0 = (wm << 6) + (lane & 15);
  int brow0 = (wn << 6) + (lane & 15);
  int koff = (lane >> 4) << 10;

  auto STAGE = [&](int it, int bufo) {
    int k0 = it << 5;
#pragma unroll
    for (int c = 0; c < 2; ++c) {
      int s = (c << 8) + tid;
      int r = s & 127, kq = s >> 7;
      int lb = (s & ~63) << 3;
      gll16(X1h + (arow0g + r) * 1024 + k0 + (kq << 3), smem + bufo + lb);
      gll16(Bh + (size_t)(col0 + r) * 1024 + k0 + (kq << 3), smem + bufo + 4096 + lb);
    }
  };

  STAGE(0, 0);
  int cur = 0;
#pragma unroll 1
  for (int it = 0; it < 32; ++it) {
    int nb = (cur ^ 1) << 13;
    if (it + 1 < 32) { STAGE(it + 1, nb); PIPE_BARRIER_VM4(); }
    else             { PIPE_BARRIER_VM0(); }
    const u16* Ab = smem + (cur << 13);
    const u16* Bb = Ab + 4096;
    bf16x8 af[4], bfh[4];
#pragma unroll
    for (int i = 0; i < 4; i++)
      af[i] = *(const bf16x8*)(Ab + koff + ((arow0 + (i << 4)) << 3));
#pragma unroll
    for (int j = 0; j < 4; j++)
      bfh[j] = *(const bf16x8*)(Bb + koff + ((brow0 + (j << 4)) << 3));
#pragma unroll
    for (int i = 0; i < 4; i++)
#pragma unroll
      for (int j = 0; j < 4; j++)
        acc[i][j] = __builtin_amdgcn_mfma_f32_16x16x32_bf16(af[i], bfh[j], acc[i][j], 0, 0, 0);
    PIPE_BARRIER_LGKM();
    cur ^= 1;
  }
  // epilogue: bias + exact gelu, LDS-staged coalesced bf16 stores
#pragma unroll
  for (int p = 0; p < 2; ++p) {
    if (wm == p) {
#pragma unroll
      for (int j = 0; j < 4; j++) {
        int fl = (wn << 6) + (j << 4) + (lane & 15);     // local col 0..127
        float bv = b1[col0 + fl];
#pragma unroll
        for (int i = 0; i < 4; i++) {
          int rl = (i << 4) + ((lane >> 4) << 2);        // local row 0..60
#pragma unroll
          for (int q = 0; q < 4; q++) {
            float v = acc[i][j][q] + bv;
            float ge = 0.5f * v * (1.0f + erff(v * 0.70710678118654752f));
            smem[(rl + q) * 132 + fl] = f2bf(ge);
          }
        }
      }
    }
    __syncthreads();
#pragma unroll
    for (int v = 0; v < 4; v++) {
      int idx = (v << 8) + tid;          // 0..1023
      int row = idx >> 4, cq = idx & 15;
      bf16x8 val = *(const bf16x8*)(smem + row * 132 + (cq << 3));
      *(bf16x8*)(Hch + (size_t)(hrow0 + (p << 6) + row) * 4096 + col0 + (cq << 3)) = val;
    }
    __syncthreads();
  }
}

// ------- FFN2 MFMA: Y = Hc @ w2^T, pure bf16, 128x128 tile, 2-phase + XCD swizzle -------
__global__ __launch_bounds__(256) void k_ffn2m(const u16* __restrict__ Hch,
                                               const u16* __restrict__ W2h,
                                               u16* __restrict__ Yb, int e) {
  __shared__ __align__(16) u16 smem[16384];
  int bid = blockIdx.x;                           // 512
  int mt = ((bid >> 6) << 3) | (bid & 7);         // 0..63
  int ct = (bid >> 3) & 7;                        // 0..7
  int chunk = mt >> 4, rloc = mt & 15;
  int arow0h = mt << 7;                           // Hc linear row
  size_t yrow0g = (size_t)chunk * 4096 + (size_t)e * 2048 + (size_t)rloc * 128;
  const u16* Bh = W2h + (size_t)e * 4194304;
  int tid = threadIdx.x, lane = tid & 63, w = tid >> 6;
  int wm = w >> 1, wn = w & 1;
  int col0 = ct << 7;
  f32x4 acc[4][4];
#pragma unroll
  for (int i = 0; i < 4; i++)
#pragma unroll
    for (int j = 0; j < 4; j++) { acc[i][j][0] = 0.f; acc[i][j][1] = 0.f; acc[i][j][2] = 0.f; acc[i][j][3] = 0.f; }
  int arow0 = (wm << 6) + (lane & 15);
  int brow0 = (wn << 6) + (lane & 15);
  int koff = (lane >> 4) << 10;

  auto STAGE = [&](int it, int bufo) {
    int k0 = it << 5;
#pragma unroll
    for (int c = 0; c < 2; ++c) {
      int s = (c << 8) + tid;
      int r = s & 127, kq = s >> 7;
      int lb = (s & ~63) << 3;
      gll16(Hch + (size_t)(arow0h + r) * 4096 + k0 + (kq << 3), smem + bufo + lb);
      gll16(Bh + (size_t)(col0 + r) * 4096 + k0 + (kq << 3), smem + bufo + 4096 + lb);
    }
  };

  STAGE(0, 0);
  int cur = 0;
#pragma unroll 1
  for (int it = 0; it < 128; ++it) {
    int nb = (cur ^ 1) << 13;
    if (it + 1 < 128) { STAGE(it + 1, nb); PIPE_BARRIER_VM4(); }
    else              { PIPE_BARRIER_VM0(); }
    const u16* Ab = smem + (cur << 13);
    const u16* Bb = Ab + 4096;
    bf16x8 af[4], bfh[4];
#pragma unroll
    for (int i = 0; i < 4; i++)
      af[i] = *(const bf16x8*)(Ab + koff + ((arow0 + (i << 4)) << 3));
#pragma unroll
    for (int j = 0; j < 4; j++)
      bfh[j] = *(const bf16x8*)(Bb + koff + ((brow0 + (j << 4)) << 3));
#pragma unroll
    for (int i = 0; i < 4; i++)
#pragma unroll
      for (int j = 0; j < 4; j++)
        acc[i][j] = __builtin_amdgcn_mfma_f32_16x16x32_bf16(af[i], bfh[j], acc[i][j], 0, 0, 0);
    PIPE_BARRIER_LGKM();
    cur ^= 1;
  }
  // epilogue: LDS-staged coalesced bf16 stores
#pragma unroll
  for (int p = 0; p < 2; ++p) {
    if (wm == p) {
#pragma unroll
      for (int j = 0; j < 4; j++) {
        int fl = (wn << 6) + (j << 4) + (lane & 15);
#pragma unroll
        for (int i = 0; i < 4; i++) {
          int rl = (i << 4) + ((lane >> 4) << 2);
#pragma unroll
          for (int q = 0; q < 4; q++)
            smem[(rl + q) * 132 + fl] = f2bf(acc[i][j][q]);
        }
      }
    }
    __syncthreads();
#pragma unroll
    for (int v = 0; v < 4; v++) {
      int idx = (v << 8) + tid;
      int row = idx >> 4, cq = idx & 15;
      bf16x8 val = *(const bf16x8*)(smem + row * 132 + (cq << 3));
      *(bf16x8*)(Yb + (yrow0g + (p << 6) + row) * 1024 + col0 + (cq << 3)) = val;
    }
    __syncthreads();
  }
}

// ------- LN2: out = LN((X1h+X1l) + s*(Y + b2); lng,lnb) -- fp32 out -------
__global__ __launch_bounds__(256) void k_ln2b(const u16* __restrict__ Yb,
                                              const u16* __restrict__ X1h, const u16* __restrict__ X1l,
                                              const float* __restrict__ b2a, const float* __restrict__ b2b,
                                              const float* __restrict__ sa, const float* __restrict__ sbp,
                                              const float* __restrict__ ga, const float* __restrict__ gb,
                                              const float* __restrict__ ba, const float* __restrict__ bbp,
                                              float* __restrict__ out) {
  __shared__ float sb[8];
  int row = blockIdx.x; int tid = threadIdx.x;
  int n = row & 4095; int e = n >> 11;
  const float* b2 = e ? b2b : b2a;
  const float* lg = e ? gb : ga;
  const float* lb = e ? bbp : ba;
  float s = e ? sbp[0] : sa[0];
  int c = tid << 2;
  ushort4 yv = *(const ushort4*)(Yb + (size_t)row * 1024 + c);
  ushort4 hv = *(const ushort4*)(X1h + (size_t)row * 1024 + c);
  ushort4 lv = *(const ushort4*)(X1l + (size_t)row * 1024 + c);
  float4 b2v = *(const float4*)(b2 + c);
  float x0 = bf2f(hv.x) + bf2f(lv.x);
  float x1 = bf2f(hv.y) + bf2f(lv.y);
  float x2 = bf2f(hv.z) + bf2f(lv.z);
  float x3 = bf2f(hv.w) + bf2f(lv.w);
  float t0 = x0 + s * (bf2f(yv.x) + b2v.x);
  float t1 = x1 + s * (bf2f(yv.y) + b2v.y);
  float t2 = x2 + s * (bf2f(yv.z) + b2v.z);
  float t3 = x3 + s * (bf2f(yv.w) + b2v.w);
  float mu = blk_sum(t0 + t1 + t2 + t3, sb, tid) * (1.0f / 1024.0f);
  float d0 = t0 - mu, d1 = t1 - mu, d2 = t2 - mu, d3 = t3 - mu;
  float var = blk_sum(d0 * d0 + d1 * d1 + d2 * d2 + d3 * d3, sb, tid) * (1.0f / 1024.0f);
  float rs = 1.0f / sqrtf(var + 1e-5f);
  float4 gv = *(const float4*)(lg + c);
  float4 bv = *(const float4*)(lb + c);
  float4 o;
  o.x = d0 * rs * gv.x + bv.x;
  o.y = d1 * rs * gv.y + bv.y;
  o.z = d2 * rs * gv.z + bv.z;
  o.w = d3 * rs * gv.w + bv.w;
  *(float4*)(out + (size_t)row * 1024 + c) = o;
}

extern "C" void kernel_launch(void* const* d_in, const int* in_sizes, int n_in,
                              void* d_out, int out_size, void* d_ws, size_t ws_size,
                              hipStream_t stream) {
  (void)out_size; (void)ws_size;
  static const int SIG[18] = {16777216, 4096, 1024, 1024,
                              4194304, 4096, 4194304, 1024, 1, 1024, 1024,
                              4194304, 4096, 4194304, 1024, 1, 1024, 1024};
  const void* P[18];
  bool exact = (n_in >= 18);
  if (exact) {
    for (int i = 0; i < 18; i++) {
      if (in_sizes[i] != SIG[i]) { exact = false; break; }
    }
  }
  if (exact) {
    for (int i = 0; i < 18; i++) P[i] = d_in[i];
  } else {
    bool used[64] = {false};
    int cap = (n_in < 64) ? n_in : 64;
    for (int r = 0; r < 18; r++) {
      int found = -1;
      for (int j = 0; j < cap; j++) {
        if (!used[j] && in_sizes[j] == SIG[r]) { found = j; break; }
      }
      if (found >= 0) { used[found] = true; P[r] = d_in[found]; }
      else            { P[r] = d_in[(r < n_in) ? r : 0]; }
    }
  }
  const float* x     = (const float*)P[0];
  const float* wv    = (const float*)P[1];
  const float* ng    = (const float*)P[2];
  const float* nb    = (const float*)P[3];
  const float* w1_0  = (const float*)P[4];
  const float* b1_0  = (const float*)P[5];
  const float* w2_0  = (const float*)P[6];
  const float* b2_0  = (const float*)P[7];
  const float* s_0   = (const float*)P[8];
  const float* lng_0 = (const float*)P[9];
  const float* lnb_0 = (const float*)P[10];
  const float* w1_1  = (const float*)P[11];
  const float* b1_1  = (const float*)P[12];
  const float* w2_1  = (const float*)P[13];
  const float* b2_1  = (const float*)P[14];
  const float* s_1   = (const float*)P[15];
  const float* lng_1 = (const float*)P[16];
  const float* lnb_1 = (const float*)P[17];

  char* ws = (char*)d_ws;
  u16* W1h = (u16*)(ws + 0);           // 16 MB: [2 experts][4096][1024] bf16
  u16* W2h = (u16*)(ws + 16777216);    // 16 MB: [2 experts][1024][4096] bf16
  u16* Xth = (u16*)(ws + 33554432);    // 32 MB [4][1024][4096]  (dead after conv -> X1h)
  u16* X1h = Xth;
  u16* X1l = (u16*)(ws + 67108864);    // 32 MB [16384][1024]
  float* U = (float*)(ws + 100663296); // 64 MB fp32 conv out (dead after LN1)
  u16* Hch = (u16*)(ws + 100663296);   // 64 MB [8192][4096] bf16 (overlays U)
  u16* Yb  = (u16*)(ws + 167772160);   // 32 MB [16384][1024]
  u16* wrh8 = (u16*)(ws + 201326592);  // 8*4352*2 = 69632 B

  k_wsplit<<<136, 256, 0, stream>>>(wv, wrh8);
  k_tsplit<<<4096, 256, 0, stream>>>(x, Xth);
  k_split<<<4096, 256, 0, stream>>>(w1_0, W1h);
  k_split<<<4096, 256, 0, stream>>>(w1_1, W1h + 4194304);
  k_split<<<4096, 256, 0, stream>>>(w2_0, W2h);
  k_split<<<4096, 256, 0, stream>>>(w2_1, W2h + 4194304);
  k_convm<<<1024, 256, 0, stream>>>(Xth, wrh8, x, U);
  k_ln1b<<<16384, 256, 0, stream>>>(U, ng, nb, X1h, X1l);
  for (int e = 0; e < 2; e++) {
    k_ffn1m<<<2048, 256, 0, stream>>>(X1h, W1h, b1_0, b1_1, Hch, e);
    k_ffn2m<<<512, 256, 0, stream>>>(Hch, W2h, Yb, e);
  }
  k_ln2b<<<16384, 256, 0, stream>>>(Yb, X1h, X1l, b2_0, b2_1, s_0, s_1,
                                    lng_0, lng_1, lnb_0, lnb_1, (float*)d_out);
}

// Round 7
// 990.558 us; speedup vs baseline: 1.2413x; 1.0133x over previous
//
#include <hip/hip_runtime.h>
#include <math.h>

typedef unsigned short u16;
typedef unsigned int u32;

using bf16x8 = __attribute__((ext_vector_type(8))) short;  // 8 bf16 (4 VGPRs)
using f32x4  = __attribute__((ext_vector_type(4))) float;  // 4 fp32 acc

__device__ __forceinline__ u16 f2bf(float f) {
  u32 u = __float_as_uint(f);
  u32 r = u + 0x7FFFu + ((u >> 16) & 1u);   // RNE
  return (u16)(r >> 16);
}
__device__ __forceinline__ float bf2f(u16 h) {
  return __uint_as_float(((u32)h) << 16);
}

// async global->LDS, 16B per lane; lds ptr must be wave-uniform base (HW adds lane*16)
__device__ __forceinline__ void gll16(const u16* g, u16* l) {
  __builtin_amdgcn_global_load_lds((const __attribute__((address_space(1))) void*)g,
                                   (__attribute__((address_space(3))) void*)l, 16, 0, 0);
}

// counted-vmcnt barrier: wait until <=N vmem ops outstanding, then barrier.
// Single asm with memory clobber so no LDS read / gll16 crosses it.
#define PIPE_BARRIER_VM4()  asm volatile("s_waitcnt vmcnt(4)\n\ts_barrier" ::: "memory")
#define PIPE_BARRIER_VM8()  asm volatile("s_waitcnt vmcnt(8)\n\ts_barrier" ::: "memory")
#define PIPE_BARRIER_VM0()  asm volatile("s_waitcnt vmcnt(0)\n\ts_barrier" ::: "memory")
#define PIPE_BARRIER_LGKM() asm volatile("s_waitcnt lgkmcnt(0)\n\ts_barrier" ::: "memory")

// ---------------- fp32 -> bf16 cast (weights) ----------------
__global__ __launch_bounds__(256) void k_split(const float* __restrict__ src,
                                               u16* __restrict__ h) {
  size_t i = ((size_t)blockIdx.x << 8) + threadIdx.x;
  float4 v = *(const float4*)(src + (i << 2));
  ushort4 hv;
  hv.x = f2bf(v.x);
  hv.y = f2bf(v.y);
  hv.z = f2bf(v.z);
  hv.w = f2bf(v.w);
  *(ushort4*)(h + (i << 2)) = hv;
}

// ------- build 8 pre-shifted reversed-w copies: wr8[p][i] = bf16(w[4095-(i+p)]), 0 if i+p>4095 -------
__global__ __launch_bounds__(256) void k_wsplit(const float* __restrict__ w,
                                                u16* __restrict__ wrh8) {
  int bid = blockIdx.x;                 // 8 * 17 = 136 blocks
  int p = bid / 17;
  int i = (bid % 17) * 256 + threadIdx.x;   // [0, 4352)
  int j = i + p;
  float v = (j <= 4095) ? w[4095 - j] : 0.0f;
  wrh8[(size_t)p * 4352 + i] = f2bf(v);
}

// ------- transpose: x [4][4096][1024] f32 -> Xth [4][1024][4096] bf16 -------
__global__ __launch_bounds__(256) void k_tsplit(const float* __restrict__ x,
                                                u16* __restrict__ Xth) {
  __shared__ float tile[64 * 65];
  int bid = blockIdx.x;
  int b = bid >> 10; int rem = bid & 1023;
  int mt = rem >> 4; int dt = rem & 15;
  int m0 = mt << 6, d0 = dt << 6;
  int tid = threadIdx.x;
  int rr = tid >> 4, cc = (tid & 15) << 2;
#pragma unroll
  for (int i = 0; i < 4; i++) {
    int r = (i << 4) + rr;   // m-row within tile
    float4 v = *(const float4*)(x + (size_t)(b * 4096 + m0 + r) * 1024 + d0 + cc);
    tile[r * 65 + cc + 0] = v.x; tile[r * 65 + cc + 1] = v.y;
    tile[r * 65 + cc + 2] = v.z; tile[r * 65 + cc + 3] = v.w;
  }
  __syncthreads();
#pragma unroll
  for (int i = 0; i < 4; i++) {
    int rd = (i << 4) + rr;  // d-row within tile
    ushort4 hv;
    hv.x = f2bf(tile[(cc + 0) * 65 + rd]);
    hv.y = f2bf(tile[(cc + 1) * 65 + rd]);
    hv.z = f2bf(tile[(cc + 2) * 65 + rd]);
    hv.w = f2bf(tile[(cc + 3) * 65 + rd]);
    size_t o = (size_t)(b * 1024 + d0 + rd) * 4096 + m0 + cc;
    *(ushort4*)(Xth + o) = hv;
  }
}

// ------- conv MFMA: U[b,n,d] = x + (sum_{m<=n} w[n-m] x[b,m,d]) * rsqrt(n+1) -------
// k-quad-major LDS [4][128][8], double-buffered, counted-vmcnt 2-phase pipeline.
__global__ __launch_bounds__(256) void k_convm(const u16* __restrict__ Xth,
                                               const u16* __restrict__ wrh8,
                                               const float* __restrict__ x,
                                               float* __restrict__ U) {
  __shared__ __align__(16) u16 smem[16384];   // 2 bufs x (A 4096 + B 4096)
  int bid = blockIdx.x;
  int nt = 31 - (bid >> 5);        // descending: heavy blocks launch first
  int b  = (bid >> 3) & 3;
  int dt = bid & 7;
  int n0 = nt << 7, d0 = dt << 7;
  int tid = threadIdx.x, lane = tid & 63, w4 = tid >> 6;
  int wm = w4 >> 1, wn = w4 & 1;
  const u16* Xbh = Xth + (size_t)b * 4194304;
  f32x4 acc[4][4];
#pragma unroll
  for (int i = 0; i < 4; i++)
#pragma unroll
    for (int j = 0; j < 4; j++) { acc[i][j][0] = 0.f; acc[i][j][1] = 0.f; acc[i][j][2] = 0.f; acc[i][j][3] = 0.f; }
  int arow0 = (wm << 6) + (lane & 15);
  int brow0 = (wn << 6) + (lane & 15);
  int koff = (lane >> 4) << 10;         // kq subtile base in u16
  int kIters = (nt << 2) + 4;           // m in [0, n0+128)

  auto STAGE = [&](int it, int bufo) {
    int m0 = it << 5;
    int C = 4095 - n0 + m0;             // A row r k-run starts at wrev[C - r]
#pragma unroll
    for (int c = 0; c < 2; ++c) {
      int s = (c << 8) + tid;
      int r = s & 127, kq = s >> 7;
      int lb = (s & ~63) << 3;          // wave-uniform u16 offset (dest = lb + lane*8)
      int base = C - r;
      int p = base & 7;
      size_t ao = (size_t)p * 4352 + (base - p) + (kq << 3);   // 16B-aligned
      gll16(wrh8 + ao, smem + bufo + lb);
      size_t go = (size_t)(d0 + r) * 4096 + m0 + (kq << 3);
      gll16(Xbh + go, smem + bufo + 4096 + lb);
    }
  };

  STAGE(0, 0);
  int cur = 0;
#pragma unroll 1
  for (int it = 0; it < kIters; ++it) {
    int nb = (cur ^ 1) << 13;
    if (it + 1 < kIters) { STAGE(it + 1, nb); PIPE_BARRIER_VM4(); }
    else                 { PIPE_BARRIER_VM0(); }
    const u16* Ab = smem + (cur << 13);
    const u16* Bb = Ab + 4096;
    bf16x8 af[4], bfh[4];
#pragma unroll
    for (int i = 0; i < 4; i++)
      af[i] = *(const bf16x8*)(Ab + koff + ((arow0 + (i << 4)) << 3));
#pragma unroll
    for (int j = 0; j < 4; j++)
      bfh[j] = *(const bf16x8*)(Bb + koff + ((brow0 + (j << 4)) << 3));
#pragma unroll
    for (int i = 0; i < 4; i++)
#pragma unroll
      for (int j = 0; j < 4; j++)
        acc[i][j] = __builtin_amdgcn_mfma_f32_16x16x32_bf16(af[i], bfh[j], acc[i][j], 0, 0, 0);
    PIPE_BARRIER_LGKM();
    cur ^= 1;
  }
  // epilogue: U[n][d] = x[n][d] + acc * rsqrt(n+1)  (fp32, sector-aligned -- direct)
#pragma unroll
  for (int i = 0; i < 4; i++) {
    int nb_ = n0 + (wm << 6) + (i << 4) + ((lane >> 4) << 2);
#pragma unroll
    for (int q = 0; q < 4; q++) {
      int n = nb_ + q;
      float scale = rsqrtf((float)(n + 1));
#pragma unroll
      for (int j = 0; j < 4; j++) {
        int d = d0 + (wn << 6) + (j << 4) + (lane & 15);
        size_t idx = ((size_t)(b * 4096 + n)) * 1024 + d;
        U[idx] = x[idx] + acc[i][j][q] * scale;
      }
    }
  }
}

// ---------------- block reduction over 256 threads (4 waves) ----------------
__device__ __forceinline__ float blk_sum(float v, float* sb, int tid) {
#pragma unroll
  for (int off = 32; off > 0; off >>= 1) v += __shfl_down(v, off, 64);
  int wid = tid >> 6;
  if ((tid & 63) == 0) sb[wid] = v;
  __syncthreads();
  if (tid == 0) sb[4] = sb[0] + sb[1] + sb[2] + sb[3];
  __syncthreads();
  return sb[4];
}

// ---------------- LN1: X1 = LN(U; g,b), emitted as bf16 hi/lo pair ----------------
__global__ __launch_bounds__(256) void k_ln1b(const float* __restrict__ U,
                                              const float* __restrict__ g,
                                              const float* __restrict__ bt,
                                              u16* __restrict__ X1h,
                                              u16* __restrict__ X1l) {
  __shared__ float sb[8];
  int row = blockIdx.x; int tid = threadIdx.x;
  int c = tid << 2;
  float4 v = *(const float4*)(U + (size_t)row * 1024 + c);
  float mu = blk_sum(v.x + v.y + v.z + v.w, sb, tid) * (1.0f / 1024.0f);
  float dx = v.x - mu, dy = v.y - mu, dz = v.z - mu, dw = v.w - mu;
  float var = blk_sum(dx * dx + dy * dy + dz * dz + dw * dw, sb, tid) * (1.0f / 1024.0f);
  float rs = 1.0f / sqrtf(var + 1e-5f);
  float4 gv = *(const float4*)(g + c);
  float4 bv = *(const float4*)(bt + c);
  float o0 = dx * rs * gv.x + bv.x;
  float o1 = dy * rs * gv.y + bv.y;
  float o2 = dz * rs * gv.z + bv.z;
  float o3 = dw * rs * gv.w + bv.w;
  ushort4 hv, lv;
  hv.x = f2bf(o0); lv.x = f2bf(o0 - bf2f(hv.x));
  hv.y = f2bf(o1); lv.y = f2bf(o1 - bf2f(hv.y));
  hv.z = f2bf(o2); lv.z = f2bf(o2 - bf2f(hv.z));
  hv.w = f2bf(o3); lv.w = f2bf(o3 - bf2f(hv.w));
  *(ushort4*)(X1h + (size_t)row * 1024 + c) = hv;
  *(ushort4*)(X1l + (size_t)row * 1024 + c) = lv;
}

// ------- FFN1 MFMA: Hc = gelu(X1 @ w1^T + b1), pure bf16, one expert per call -------
// R4-proven block order (ct fastest: A panel shared by consecutive blocks) + 2-phase pipeline.
__global__ __launch_bounds__(256) void k_ffn1m(const u16* __restrict__ X1h,
                                               const u16* __restrict__ W1h,
                                               const float* __restrict__ b1a, const float* __restrict__ b1b,
                                               u16* __restrict__ Hch, int e) {
  __shared__ __align__(16) u16 smem[16384];
  int bid = blockIdx.x;                           // 2048
  int mt = bid >> 5;                              // 0..63  (ct fastest -- R4 order)
  int ct = bid & 31;                              // 0..31
  int chunk = mt >> 4, rloc = mt & 15;
  size_t arow0g = (size_t)chunk * 4096 + (size_t)e * 2048 + (size_t)rloc * 128;
  int hrow0 = mt << 7;
  const u16* Bh = W1h + (size_t)e * 4194304;
  const float* b1 = e ? b1b : b1a;
  int tid = threadIdx.x, lane = tid & 63, w = tid >> 6;
  int wm = w >> 1, wn = w & 1;
  int col0 = ct << 7;
  f32x4 acc[4][4];
#pragma unroll
  for (int i = 0; i < 4; i++)
#pragma unroll
    for (int j = 0; j < 4; j++) { acc[i][j][0] = 0.f; acc[i][j][1] = 0.f; acc[i][j][2] = 0.f; acc[i][j][3] = 0.f; }
  int arow0 = (wm << 6) + (lane & 15);
  int brow0 = (wn << 6) + (lane & 15);
  int koff = (lane >> 4) << 10;

  auto STAGE = [&](int it, int bufo) {
    int k0 = it << 5;
#pragma unroll
    for (int c = 0; c < 2; ++c) {
      int s = (c << 8) + tid;
      int r = s & 127, kq = s >> 7;
      int lb = (s & ~63) << 3;
      gll16(X1h + (arow0g + r) * 1024 + k0 + (kq << 3), smem + bufo + lb);
      gll16(Bh + (size_t)(col0 + r) * 1024 + k0 + (kq << 3), smem + bufo + 4096 + lb);
    }
  };

  STAGE(0, 0);
  int cur = 0;
#pragma unroll 1
  for (int it = 0; it < 32; ++it) {
    int nb = (cur ^ 1) << 13;
    if (it + 1 < 32) { STAGE(it + 1, nb); PIPE_BARRIER_VM4(); }
    else             { PIPE_BARRIER_VM0(); }
    const u16* Ab = smem + (cur << 13);
    const u16* Bb = Ab + 4096;
    bf16x8 af[4], bfh[4];
#pragma unroll
    for (int i = 0; i < 4; i++)
      af[i] = *(const bf16x8*)(Ab + koff + ((arow0 + (i << 4)) << 3));
#pragma unroll
    for (int j = 0; j < 4; j++)
      bfh[j] = *(const bf16x8*)(Bb + koff + ((brow0 + (j << 4)) << 3));
#pragma unroll
    for (int i = 0; i < 4; i++)
#pragma unroll
      for (int j = 0; j < 4; j++)
        acc[i][j] = __builtin_amdgcn_mfma_f32_16x16x32_bf16(af[i], bfh[j], acc[i][j], 0, 0, 0);
    PIPE_BARRIER_LGKM();
    cur ^= 1;
  }
  // epilogue: bias + exact gelu, LDS-staged coalesced bf16 stores
#pragma unroll
  for (int p = 0; p < 2; ++p) {
    if (wm == p) {
#pragma unroll
      for (int j = 0; j < 4; j++) {
        int fl = (wn << 6) + (j << 4) + (lane & 15);     // local col 0..127
        float bv = b1[col0 + fl];
#pragma unroll
        for (int i = 0; i < 4; i++) {
          int rl = (i << 4) + ((lane >> 4) << 2);        // local row 0..60
#pragma unroll
          for (int q = 0; q < 4; q++) {
            float v = acc[i][j][q] + bv;
            float ge = 0.5f * v * (1.0f + erff(v * 0.70710678118654752f));
            smem[(rl + q) * 132 + fl] = f2bf(ge);
          }
        }
      }
    }
    __syncthreads();
#pragma unroll
    for (int v = 0; v < 4; v++) {
      int idx = (v << 8) + tid;          // 0..1023
      int row = idx >> 4, cq = idx & 15;
      bf16x8 val = *(const bf16x8*)(smem + row * 132 + (cq << 3));
      *(bf16x8*)(Hch + (size_t)(hrow0 + (p << 6) + row) * 4096 + col0 + (cq << 3)) = val;
    }
    __syncthreads();
  }
}

// ------- FFN2 MFMA: Y = Hc @ w2^T, pure bf16, 128x128 tile, BK=64, 2-phase + XCD swizzle -------
__global__ __launch_bounds__(256) void k_ffn2m(const u16* __restrict__ Hch,
                                               const u16* __restrict__ W2h,
                                               u16* __restrict__ Yb, int e) {
  __shared__ __align__(16) u16 smem[32768];       // 2 bufs x (A 8192 + B 8192) u16 = 64 KB
  int bid = blockIdx.x;                           // 512
  int mt = ((bid >> 6) << 3) | (bid & 7);         // 0..63 (per-XCD 8mt x 8ct -- R6 proven)
  int ct = (bid >> 3) & 7;                        // 0..7
  int chunk = mt >> 4, rloc = mt & 15;
  int arow0h = mt << 7;                           // Hc linear row
  size_t yrow0g = (size_t)chunk * 4096 + (size_t)e * 2048 + (size_t)rloc * 128;
  const u16* Bh = W2h + (size_t)e * 4194304;
  int tid = threadIdx.x, lane = tid & 63, w = tid >> 6;
  int wm = w >> 1, wn = w & 1;
  int col0 = ct << 7;
  f32x4 acc[4][4];
#pragma unroll
  for (int i = 0; i < 4; i++)
#pragma unroll
    for (int j = 0; j < 4; j++) { acc[i][j][0] = 0.f; acc[i][j][1] = 0.f; acc[i][j][2] = 0.f; acc[i][j][3] = 0.f; }
  int arow0 = (wm << 6) + (lane & 15);
  int brow0 = (wn << 6) + (lane & 15);

  auto STAGE = [&](int it, int bufo) {
    int k0 = it << 6;
#pragma unroll
    for (int c = 0; c < 4; ++c) {                 // 1024 slots: [8 kq][128 r][8 u16]
      int s = (c << 8) + tid;
      int r = s & 127, kq = s >> 7;
      int lb = (s & ~63) << 3;
      gll16(Hch + (size_t)(arow0h + r) * 4096 + k0 + (kq << 3), smem + bufo + lb);
      gll16(Bh + (size_t)(col0 + r) * 4096 + k0 + (kq << 3), smem + bufo + 8192 + lb);
    }
  };

  STAGE(0, 0);
  int cur = 0;
#pragma unroll 1
  for (int it = 0; it < 64; ++it) {
    int nb = (cur ^ 1) << 14;
    if (it + 1 < 64) { STAGE(it + 1, nb); PIPE_BARRIER_VM8(); }
    else             { PIPE_BARRIER_VM0(); }
    const u16* Ab = smem + (cur << 14);
    const u16* Bb = Ab + 8192;
#pragma unroll
    for (int ks = 0; ks < 2; ++ks) {
      int koff2 = ((ks << 2) + (lane >> 4)) << 10;
      bf16x8 af[4], bfh[4];
#pragma unroll
      for (int i = 0; i < 4; i++)
        af[i] = *(const bf16x8*)(Ab + koff2 + ((arow0 + (i << 4)) << 3));
#pragma unroll
      for (int j = 0; j < 4; j++)
        bfh[j] = *(const bf16x8*)(Bb + koff2 + ((brow0 + (j << 4)) << 3));
#pragma unroll
      for (int i = 0; i < 4; i++)
#pragma unroll
        for (int j = 0; j < 4; j++)
          acc[i][j] = __builtin_amdgcn_mfma_f32_16x16x32_bf16(af[i], bfh[j], acc[i][j], 0, 0, 0);
    }
    PIPE_BARRIER_LGKM();
    cur ^= 1;
  }
  // epilogue: LDS-staged coalesced bf16 stores
#pragma unroll
  for (int p = 0; p < 2; ++p) {
    if (wm == p) {
#pragma unroll
      for (int j = 0; j < 4; j++) {
        int fl = (wn << 6) + (j << 4) + (lane & 15);
#pragma unroll
        for (int i = 0; i < 4; i++) {
          int rl = (i << 4) + ((lane >> 4) << 2);
#pragma unroll
          for (int q = 0; q < 4; q++)
            smem[(rl + q) * 132 + fl] = f2bf(acc[i][j][q]);
        }
      }
    }
    __syncthreads();
#pragma unroll
    for (int v = 0; v < 4; v++) {
      int idx = (v << 8) + tid;
      int row = idx >> 4, cq = idx & 15;
      bf16x8 val = *(const bf16x8*)(smem + row * 132 + (cq << 3));
      *(bf16x8*)(Yb + (yrow0g + (p << 6) + row) * 1024 + col0 + (cq << 3)) = val;
    }
    __syncthreads();
  }
}

// ------- LN2: out = LN((X1h+X1l) + s*(Y + b2); lng,lnb) -- fp32 out -------
__global__ __launch_bounds__(256) void k_ln2b(const u16* __restrict__ Yb,
                                              const u16* __restrict__ X1h, const u16* __restrict__ X1l,
                                              const float* __restrict__ b2a, const float* __restrict__ b2b,
                                              const float* __restrict__ sa, const float* __restrict__ sbp,
                                              const float* __restrict__ ga, const float* __restrict__ gb,
                                              const float* __restrict__ ba, const float* __restrict__ bbp,
                                              float* __restrict__ out) {
  __shared__ float sb[8];
  int row = blockIdx.x; int tid = threadIdx.x;
  int n = row & 4095; int e = n >> 11;
  const float* b2 = e ? b2b : b2a;
  const float* lg = e ? gb : ga;
  const float* lb = e ? bbp : ba;
  float s = e ? sbp[0] : sa[0];
  int c = tid << 2;
  ushort4 yv = *(const ushort4*)(Yb + (size_t)row * 1024 + c);
  ushort4 hv = *(const ushort4*)(X1h + (size_t)row * 1024 + c);
  ushort4 lv = *(const ushort4*)(X1l + (size_t)row * 1024 + c);
  float4 b2v = *(const float4*)(b2 + c);
  float x0 = bf2f(hv.x) + bf2f(lv.x);
  float x1 = bf2f(hv.y) + bf2f(lv.y);
  float x2 = bf2f(hv.z) + bf2f(lv.z);
  float x3 = bf2f(hv.w) + bf2f(lv.w);
  float t0 = x0 + s * (bf2f(yv.x) + b2v.x);
  float t1 = x1 + s * (bf2f(yv.y) + b2v.y);
  float t2 = x2 + s * (bf2f(yv.z) + b2v.z);
  float t3 = x3 + s * (bf2f(yv.w) + b2v.w);
  float mu = blk_sum(t0 + t1 + t2 + t3, sb, tid) * (1.0f / 1024.0f);
  float d0 = t0 - mu, d1 = t1 - mu, d2 = t2 - mu, d3 = t3 - mu;
  float var = blk_sum(d0 * d0 + d1 * d1 + d2 * d2 + d3 * d3, sb, tid) * (1.0f / 1024.0f);
  float rs = 1.0f / sqrtf(var + 1e-5f);
  float4 gv = *(const float4*)(lg + c);
  float4 bv = *(const float4*)(lb + c);
  float4 o;
  o.x = d0 * rs * gv.x + bv.x;
  o.y = d1 * rs * gv.y + bv.y;
  o.z = d2 * rs * gv.z + bv.z;
  o.w = d3 * rs * gv.w + bv.w;
  *(float4*)(out + (size_t)row * 1024 + c) = o;
}

extern "C" void kernel_launch(void* const* d_in, const int* in_sizes, int n_in,
                              void* d_out, int out_size, void* d_ws, size_t ws_size,
                              hipStream_t stream) {
  (void)out_size; (void)ws_size;
  static const int SIG[18] = {16777216, 4096, 1024, 1024,
                              4194304, 4096, 4194304, 1024, 1, 1024, 1024,
                              4194304, 4096, 4194304, 1024, 1, 1024, 1024};
  const void* P[18];
  bool exact = (n_in >= 18);
  if (exact) {
    for (int i = 0; i < 18; i++) {
      if (in_sizes[i] != SIG[i]) { exact = false; break; }
    }
  }
  if (exact) {
    for (int i = 0; i < 18; i++) P[i] = d_in[i];
  } else {
    bool used[64] = {false};
    int cap = (n_in < 64) ? n_in : 64;
    for (int r = 0; r < 18; r++) {
      int found = -1;
      for (int j = 0; j < cap; j++) {
        if (!used[j] && in_sizes[j] == SIG[r]) { found = j; break; }
      }
      if (found >= 0) { used[found] = true; P[r] = d_in[found]; }
      else            { P[r] = d_in[(r < n_in) ? r : 0]; }
    }
  }
  const float* x     = (const float*)P[0];
  const float* wv    = (const float*)P[1];
  const float* ng    = (const float*)P[2];
  const float* nb    = (const float*)P[3];
  const float* w1_0  = (const float*)P[4];
  const float* b1_0  = (const float*)P[5];
  const float* w2_0  = (const float*)P[6];
  const float* b2_0  = (const float*)P[7];
  const float* s_0   = (const float*)P[8];
  const float* lng_0 = (const float*)P[9];
  const float* lnb_0 = (const float*)P[10];
  const float* w1_1  = (const float*)P[11];
  const float* b1_1  = (const float*)P[12];
  const float* w2_1  = (const float*)P[13];
  const float* b2_1  = (const float*)P[14];
  const float* s_1   = (const float*)P[15];
  const float* lng_1 = (const float*)P[16];
  const float* lnb_1 = (const float*)P[17];

  char* ws = (char*)d_ws;
  u16* W1h = (u16*)(ws + 0);           // 16 MB: [2 experts][4096][1024] bf16
  u16* W2h = (u16*)(ws + 16777216);    // 16 MB: [2 experts][1024][4096] bf16
  u16* Xth = (u16*)(ws + 33554432);    // 32 MB [4][1024][4096]  (dead after conv -> X1h)
  u16* X1h = Xth;
  u16* X1l = (u16*)(ws + 67108864);    // 32 MB [16384][1024]
  float* U = (float*)(ws + 100663296); // 64 MB fp32 conv out (dead after LN1)
  u16* Hch = (u16*)(ws + 100663296);   // 64 MB [8192][4096] bf16 (overlays U)
  u16* Yb  = (u16*)(ws + 167772160);   // 32 MB [16384][1024]
  u16* wrh8 = (u16*)(ws + 201326592);  // 8*4352*2 = 69632 B

  k_wsplit<<<136, 256, 0, stream>>>(wv, wrh8);
  k_tsplit<<<4096, 256, 0, stream>>>(x, Xth);
  k_split<<<4096, 256, 0, stream>>>(w1_0, W1h);
  k_split<<<4096, 256, 0, stream>>>(w1_1, W1h + 4194304);
  k_split<<<4096, 256, 0, stream>>>(w2_0, W2h);
  k_split<<<4096, 256, 0, stream>>>(w2_1, W2h + 4194304);
  k_convm<<<1024, 256, 0, stream>>>(Xth, wrh8, x, U);
  k_ln1b<<<16384, 256, 0, stream>>>(U, ng, nb, X1h, X1l);
  for (int e = 0; e < 2; e++) {
    k_ffn1m<<<2048, 256, 0, stream>>>(X1h, W1h, b1_0, b1_1, Hch, e);
    k_ffn2m<<<512, 256, 0, stream>>>(Hch, W2h, Yb, e);
  }
  k_ln2b<<<16384, 256, 0, stream>>>(Yb, X1h, X1l, b2_0, b2_1, s_0, s_1,
                                    lng_0, lng_1, lnb_0, lnb_1, (float*)d_out);
}

// Round 8
// 701.052 us; speedup vs baseline: 1.7539x; 1.4130x over previous
//
#include <hip/hip_runtime.h>
#include <math.h>

typedef unsigned short u16;
typedef unsigned int u32;

using bf16x8 = __attribute__((ext_vector_type(8))) short;  // 8 bf16 (4 VGPRs)
using f32x4  = __attribute__((ext_vector_type(4))) float;  // 4 fp32 acc

__device__ __forceinline__ u16 f2bf(float f) {
  u32 u = __float_as_uint(f);
  u32 r = u + 0x7FFFu + ((u >> 16) & 1u);   // RNE
  return (u16)(r >> 16);
}
__device__ __forceinline__ float bf2f(u16 h) {
  return __uint_as_float(((u32)h) << 16);
}

// async global->LDS, 16B per lane; lds ptr must be wave-uniform base (HW adds lane*16)
__device__ __forceinline__ void gll16(const u16* g, u16* l) {
  __builtin_amdgcn_global_load_lds((const __attribute__((address_space(1))) void*)g,
                                   (__attribute__((address_space(3))) void*)l, 16, 0, 0);
}

// counted-vmcnt barrier: wait until <=N vmem ops outstanding, then barrier.
#define PIPE_BARRIER_VM4()  asm volatile("s_waitcnt vmcnt(4)\n\ts_barrier" ::: "memory")
#define PIPE_BARRIER_VM8()  asm volatile("s_waitcnt vmcnt(8)\n\ts_barrier" ::: "memory")
#define PIPE_BARRIER_VM0()  asm volatile("s_waitcnt vmcnt(0)\n\ts_barrier" ::: "memory")
#define PIPE_BARRIER_LGKM() asm volatile("s_waitcnt lgkmcnt(0)\n\ts_barrier" ::: "memory")

// ---------------- fp32 -> bf16 cast (weights) ----------------
__global__ __launch_bounds__(256) void k_split(const float* __restrict__ src,
                                               u16* __restrict__ h) {
  size_t i = ((size_t)blockIdx.x << 8) + threadIdx.x;
  float4 v = *(const float4*)(src + (i << 2));
  ushort4 hv;
  hv.x = f2bf(v.x);
  hv.y = f2bf(v.y);
  hv.z = f2bf(v.z);
  hv.w = f2bf(v.w);
  *(ushort4*)(h + (i << 2)) = hv;
}

// ------- build 8 pre-shifted reversed-w copies: wr8[p][i] = bf16(w[4095-(i+p)]), 0 if i+p>4095 -------
__global__ __launch_bounds__(256) void k_wsplit(const float* __restrict__ w,
                                                u16* __restrict__ wrh8) {
  int bid = blockIdx.x;                 // 8 * 17 = 136 blocks
  int p = bid / 17;
  int i = (bid % 17) * 256 + threadIdx.x;   // [0, 4352)
  int j = i + p;
  float v = (j <= 4095) ? w[4095 - j] : 0.0f;
  wrh8[(size_t)p * 4352 + i] = f2bf(v);
}

// ------- transpose: x [4][4096][1024] f32 -> Xth [4][1024][4096] bf16 -------
__global__ __launch_bounds__(256) void k_tsplit(const float* __restrict__ x,
                                                u16* __restrict__ Xth) {
  __shared__ float tile[64 * 65];
  int bid = blockIdx.x;
  int b = bid >> 10; int rem = bid & 1023;
  int mt = rem >> 4; int dt = rem & 15;
  int m0 = mt << 6, d0 = dt << 6;
  int tid = threadIdx.x;
  int rr = tid >> 4, cc = (tid & 15) << 2;
#pragma unroll
  for (int i = 0; i < 4; i++) {
    int r = (i << 4) + rr;   // m-row within tile
    float4 v = *(const float4*)(x + (size_t)(b * 4096 + m0 + r) * 1024 + d0 + cc);
    tile[r * 65 + cc + 0] = v.x; tile[r * 65 + cc + 1] = v.y;
    tile[r * 65 + cc + 2] = v.z; tile[r * 65 + cc + 3] = v.w;
  }
  __syncthreads();
#pragma unroll
  for (int i = 0; i < 4; i++) {
    int rd = (i << 4) + rr;  // d-row within tile
    ushort4 hv;
    hv.x = f2bf(tile[(cc + 0) * 65 + rd]);
    hv.y = f2bf(tile[(cc + 1) * 65 + rd]);
    hv.z = f2bf(tile[(cc + 2) * 65 + rd]);
    hv.w = f2bf(tile[(cc + 3) * 65 + rd]);
    size_t o = (size_t)(b * 1024 + d0 + rd) * 4096 + m0 + cc;
    *(ushort4*)(Xth + o) = hv;
  }
}

// ------- conv MFMA: U[b,n,d] = x + (sum_{m<=n} w[n-m] x[b,m,d]) * rsqrt(n+1) -------
// Row-major LDS [128][32] with per-row chunk-XOR swizzle: slot (r,kqs) holds chunk kqs^((r>>1)&3).
// Staging stays coalesced (16x64B per wave), fragment reads at b128 bank floor.
__global__ __launch_bounds__(256) void k_convm(const u16* __restrict__ Xth,
                                               const u16* __restrict__ wrh8,
                                               const float* __restrict__ x,
                                               float* __restrict__ U) {
  __shared__ __align__(16) u16 smem[16384];   // 2 bufs x (A 4096 + B 4096)
  int bid = blockIdx.x;
  int nt = 31 - (bid >> 5);        // descending: heavy blocks launch first
  int b  = (bid >> 3) & 3;
  int dt = bid & 7;
  int n0 = nt << 7, d0 = dt << 7;
  int tid = threadIdx.x, lane = tid & 63, w4 = tid >> 6;
  int wm = w4 >> 1, wn = w4 & 1;
  const u16* Xbh = Xth + (size_t)b * 4194304;
  f32x4 acc[4][4];
#pragma unroll
  for (int i = 0; i < 4; i++)
#pragma unroll
    for (int j = 0; j < 4; j++) { acc[i][j][0] = 0.f; acc[i][j][1] = 0.f; acc[i][j][2] = 0.f; acc[i][j][3] = 0.f; }
  int arow0 = (wm << 6) + (lane & 15);
  int brow0 = (wn << 6) + (lane & 15);
  int gsw = ((lane >> 4) ^ ((lane >> 1) & 3)) << 3;   // swizzled chunk offset (u16)
  int kIters = (nt << 2) + 4;           // m in [0, n0+128)

  auto STAGE = [&](int it, int bufo) {
    int m0 = it << 5;
    int C = 4095 - n0 + m0;             // A row r k-run starts at wrev[C - r]
#pragma unroll
    for (int c = 0; c < 2; ++c) {
      int s = (c << 8) + tid;
      int r = s >> 2, kq = (s & 3) ^ ((r >> 1) & 3);
      int lb = (s & ~63) << 3;          // wave-uniform u16 offset (dest = lb + lane*16B)
      int base = C - r;
      int p = base & 7;
      size_t ao = (size_t)p * 4352 + (base - p) + (kq << 3);   // 16B-aligned
      gll16(wrh8 + ao, smem + bufo + lb);
      size_t go = (size_t)(d0 + r) * 4096 + m0 + (kq << 3);
      gll16(Xbh + go, smem + bufo + 4096 + lb);
    }
  };

  STAGE(0, 0);
  int cur = 0;
#pragma unroll 1
  for (int it = 0; it < kIters; ++it) {
    int nb = (cur ^ 1) << 13;
    if (it + 1 < kIters) { STAGE(it + 1, nb); PIPE_BARRIER_VM4(); }
    else                 { PIPE_BARRIER_VM0(); }
    const u16* Ab = smem + (cur << 13);
    const u16* Bb = Ab + 4096;
    bf16x8 af[4], bfh[4];
#pragma unroll
    for (int i = 0; i < 4; i++)
      af[i] = *(const bf16x8*)(Ab + ((arow0 + (i << 4)) << 5) + gsw);
#pragma unroll
    for (int j = 0; j < 4; j++)
      bfh[j] = *(const bf16x8*)(Bb + ((brow0 + (j << 4)) << 5) + gsw);
#pragma unroll
    for (int i = 0; i < 4; i++)
#pragma unroll
      for (int j = 0; j < 4; j++)
        acc[i][j] = __builtin_amdgcn_mfma_f32_16x16x32_bf16(af[i], bfh[j], acc[i][j], 0, 0, 0);
    PIPE_BARRIER_LGKM();
    cur ^= 1;
  }
  // epilogue: U[n][d] = x[n][d] + acc * rsqrt(n+1)  (fp32, sector-aligned -- direct)
#pragma unroll
  for (int i = 0; i < 4; i++) {
    int nb_ = n0 + (wm << 6) + (i << 4) + ((lane >> 4) << 2);
#pragma unroll
    for (int q = 0; q < 4; q++) {
      int n = nb_ + q;
      float scale = rsqrtf((float)(n + 1));
#pragma unroll
      for (int j = 0; j < 4; j++) {
        int d = d0 + (wn << 6) + (j << 4) + (lane & 15);
        size_t idx = ((size_t)(b * 4096 + n)) * 1024 + d;
        U[idx] = x[idx] + acc[i][j][q] * scale;
      }
    }
  }
}

// ---------------- block reduction over 256 threads (4 waves) ----------------
__device__ __forceinline__ float blk_sum(float v, float* sb, int tid) {
#pragma unroll
  for (int off = 32; off > 0; off >>= 1) v += __shfl_down(v, off, 64);
  int wid = tid >> 6;
  if ((tid & 63) == 0) sb[wid] = v;
  __syncthreads();
  if (tid == 0) sb[4] = sb[0] + sb[1] + sb[2] + sb[3];
  __syncthreads();
  return sb[4];
}

// ---------------- LN1: X1 = LN(U; g,b), emitted as bf16 hi/lo pair ----------------
__global__ __launch_bounds__(256) void k_ln1b(const float* __restrict__ U,
                                              const float* __restrict__ g,
                                              const float* __restrict__ bt,
                                              u16* __restrict__ X1h,
                                              u16* __restrict__ X1l) {
  __shared__ float sb[8];
  int row = blockIdx.x; int tid = threadIdx.x;
  int c = tid << 2;
  float4 v = *(const float4*)(U + (size_t)row * 1024 + c);
  float mu = blk_sum(v.x + v.y + v.z + v.w, sb, tid) * (1.0f / 1024.0f);
  float dx = v.x - mu, dy = v.y - mu, dz = v.z - mu, dw = v.w - mu;
  float var = blk_sum(dx * dx + dy * dy + dz * dz + dw * dw, sb, tid) * (1.0f / 1024.0f);
  float rs = 1.0f / sqrtf(var + 1e-5f);
  float4 gv = *(const float4*)(g + c);
  float4 bv = *(const float4*)(bt + c);
  float o0 = dx * rs * gv.x + bv.x;
  float o1 = dy * rs * gv.y + bv.y;
  float o2 = dz * rs * gv.z + bv.z;
  float o3 = dw * rs * gv.w + bv.w;
  ushort4 hv, lv;
  hv.x = f2bf(o0); lv.x = f2bf(o0 - bf2f(hv.x));
  hv.y = f2bf(o1); lv.y = f2bf(o1 - bf2f(hv.y));
  hv.z = f2bf(o2); lv.z = f2bf(o2 - bf2f(hv.z));
  hv.w = f2bf(o3); lv.w = f2bf(o3 - bf2f(hv.w));
  *(ushort4*)(X1h + (size_t)row * 1024 + c) = hv;
  *(ushort4*)(X1l + (size_t)row * 1024 + c) = lv;
}

// ------- FFN1 MFMA: Hc = gelu(X1 @ w1^T + b1), pure bf16, one expert per call -------
// R4 block order (ct fastest) + 2-phase pipeline + chunk-XOR swizzled row-major LDS.
__global__ __launch_bounds__(256) void k_ffn1m(const u16* __restrict__ X1h,
                                               const u16* __restrict__ W1h,
                                               const float* __restrict__ b1a, const float* __restrict__ b1b,
                                               u16* __restrict__ Hch, int e) {
  __shared__ __align__(16) u16 smem[16384];
  int bid = blockIdx.x;                           // 2048
  int mt = bid >> 5;                              // 0..63  (ct fastest -- R4 order)
  int ct = bid & 31;                              // 0..31
  int chunk = mt >> 4, rloc = mt & 15;
  size_t arow0g = (size_t)chunk * 4096 + (size_t)e * 2048 + (size_t)rloc * 128;
  int hrow0 = mt << 7;
  const u16* Bh = W1h + (size_t)e * 4194304;
  const float* b1 = e ? b1b : b1a;
  int tid = threadIdx.x, lane = tid & 63, w = tid >> 6;
  int wm = w >> 1, wn = w & 1;
  int col0 = ct << 7;
  f32x4 acc[4][4];
#pragma unroll
  for (int i = 0; i < 4; i++)
#pragma unroll
    for (int j = 0; j < 4; j++) { acc[i][j][0] = 0.f; acc[i][j][1] = 0.f; acc[i][j][2] = 0.f; acc[i][j][3] = 0.f; }
  int arow0 = (wm << 6) + (lane & 15);
  int brow0 = (wn << 6) + (lane & 15);
  int gsw = ((lane >> 4) ^ ((lane >> 1) & 3)) << 3;

  auto STAGE = [&](int it, int bufo) {
    int k0 = it << 5;
#pragma unroll
    for (int c = 0; c < 2; ++c) {
      int s = (c << 8) + tid;
      int r = s >> 2, kq = (s & 3) ^ ((r >> 1) & 3);
      int lb = (s & ~63) << 3;
      gll16(X1h + (arow0g + r) * 1024 + k0 + (kq << 3), smem + bufo + lb);
      gll16(Bh + (size_t)(col0 + r) * 1024 + k0 + (kq << 3), smem + bufo + 4096 + lb);
    }
  };

  STAGE(0, 0);
  int cur = 0;
#pragma unroll 1
  for (int it = 0; it < 32; ++it) {
    int nb = (cur ^ 1) << 13;
    if (it + 1 < 32) { STAGE(it + 1, nb); PIPE_BARRIER_VM4(); }
    else             { PIPE_BARRIER_VM0(); }
    const u16* Ab = smem + (cur << 13);
    const u16* Bb = Ab + 4096;
    bf16x8 af[4], bfh[4];
#pragma unroll
    for (int i = 0; i < 4; i++)
      af[i] = *(const bf16x8*)(Ab + ((arow0 + (i << 4)) << 5) + gsw);
#pragma unroll
    for (int j = 0; j < 4; j++)
      bfh[j] = *(const bf16x8*)(Bb + ((brow0 + (j << 4)) << 5) + gsw);
#pragma unroll
    for (int i = 0; i < 4; i++)
#pragma unroll
      for (int j = 0; j < 4; j++)
        acc[i][j] = __builtin_amdgcn_mfma_f32_16x16x32_bf16(af[i], bfh[j], acc[i][j], 0, 0, 0);
    PIPE_BARRIER_LGKM();
    cur ^= 1;
  }
  // epilogue: bias + exact gelu, LDS-staged coalesced bf16 stores
#pragma unroll
  for (int p = 0; p < 2; ++p) {
    if (wm == p) {
#pragma unroll
      for (int j = 0; j < 4; j++) {
        int fl = (wn << 6) + (j << 4) + (lane & 15);     // local col 0..127
        float bv = b1[col0 + fl];
#pragma unroll
        for (int i = 0; i < 4; i++) {
          int rl = (i << 4) + ((lane >> 4) << 2);        // local row 0..60
#pragma unroll
          for (int q = 0; q < 4; q++) {
            float v = acc[i][j][q] + bv;
            float ge = 0.5f * v * (1.0f + erff(v * 0.70710678118654752f));
            smem[(rl + q) * 132 + fl] = f2bf(ge);
          }
        }
      }
    }
    __syncthreads();
#pragma unroll
    for (int v = 0; v < 4; v++) {
      int idx = (v << 8) + tid;          // 0..1023
      int row = idx >> 4, cq = idx & 15;
      bf16x8 val = *(const bf16x8*)(smem + row * 132 + (cq << 3));
      *(bf16x8*)(Hch + (size_t)(hrow0 + (p << 6) + row) * 4096 + col0 + (cq << 3)) = val;
    }
    __syncthreads();
  }
}

// ------- FFN2 MFMA: Y = Hc @ w2^T, pure bf16, 128x128 tile, BK=64, 2-phase + XCD swizzle -------
// Row-major LDS [128][64] with per-row 3-bit chunk-XOR swizzle (^ (r&7)).
__global__ __launch_bounds__(256) void k_ffn2m(const u16* __restrict__ Hch,
                                               const u16* __restrict__ W2h,
                                               u16* __restrict__ Yb, int e) {
  __shared__ __align__(16) u16 smem[32768];       // 2 bufs x (A 8192 + B 8192) u16 = 64 KB
  int bid = blockIdx.x;                           // 512
  int mt = ((bid >> 6) << 3) | (bid & 7);         // 0..63 (per-XCD 8mt x 8ct -- R6 proven)
  int ct = (bid >> 3) & 7;                        // 0..7
  int chunk = mt >> 4, rloc = mt & 15;
  int arow0h = mt << 7;                           // Hc linear row
  size_t yrow0g = (size_t)chunk * 4096 + (size_t)e * 2048 + (size_t)rloc * 128;
  const u16* Bh = W2h + (size_t)e * 4194304;
  int tid = threadIdx.x, lane = tid & 63, w = tid >> 6;
  int wm = w >> 1, wn = w & 1;
  int col0 = ct << 7;
  f32x4 acc[4][4];
#pragma unroll
  for (int i = 0; i < 4; i++)
#pragma unroll
    for (int j = 0; j < 4; j++) { acc[i][j][0] = 0.f; acc[i][j][1] = 0.f; acc[i][j][2] = 0.f; acc[i][j][3] = 0.f; }
  int arow0 = (wm << 6) + (lane & 15);
  int brow0 = (wn << 6) + (lane & 15);

  auto STAGE = [&](int it, int bufo) {
    int k0 = it << 6;
#pragma unroll
    for (int c = 0; c < 4; ++c) {                 // 1024 slots: [128 r][8 kqs][8 u16]
      int s = (c << 8) + tid;
      int r = s >> 3, kq = (s & 7) ^ (r & 7);
      int lb = (s & ~63) << 3;
      gll16(Hch + (size_t)(arow0h + r) * 4096 + k0 + (kq << 3), smem + bufo + lb);
      gll16(Bh + (size_t)(col0 + r) * 4096 + k0 + (kq << 3), smem + bufo + 8192 + lb);
    }
  };

  STAGE(0, 0);
  int cur = 0;
#pragma unroll 1
  for (int it = 0; it < 64; ++it) {
    int nb = (cur ^ 1) << 14;
    if (it + 1 < 64) { STAGE(it + 1, nb); PIPE_BARRIER_VM8(); }
    else             { PIPE_BARRIER_VM0(); }
    const u16* Ab = smem + (cur << 14);
    const u16* Bb = Ab + 8192;
#pragma unroll
    for (int ks = 0; ks < 2; ++ks) {
      int ksw = (((ks << 2) + (lane >> 4)) ^ (lane & 7)) << 3;
      bf16x8 af[4], bfh[4];
#pragma unroll
      for (int i = 0; i < 4; i++)
        af[i] = *(const bf16x8*)(Ab + ((arow0 + (i << 4)) << 6) + ksw);
#pragma unroll
      for (int j = 0; j < 4; j++)
        bfh[j] = *(const bf16x8*)(Bb + ((brow0 + (j << 4)) << 6) + ksw);
#pragma unroll
      for (int i = 0; i < 4; i++)
#pragma unroll
        for (int j = 0; j < 4; j++)
          acc[i][j] = __builtin_amdgcn_mfma_f32_16x16x32_bf16(af[i], bfh[j], acc[i][j], 0, 0, 0);
    }
    PIPE_BARRIER_LGKM();
    cur ^= 1;
  }
  // epilogue: LDS-staged coalesced bf16 stores
#pragma unroll
  for (int p = 0; p < 2; ++p) {
    if (wm == p) {
#pragma unroll
      for (int j = 0; j < 4; j++) {
        int fl = (wn << 6) + (j << 4) + (lane & 15);
#pragma unroll
        for (int i = 0; i < 4; i++) {
          int rl = (i << 4) + ((lane >> 4) << 2);
#pragma unroll
          for (int q = 0; q < 4; q++)
            smem[(rl + q) * 132 + fl] = f2bf(acc[i][j][q]);
        }
      }
    }
    __syncthreads();
#pragma unroll
    for (int v = 0; v < 4; v++) {
      int idx = (v << 8) + tid;
      int row = idx >> 4, cq = idx & 15;
      bf16x8 val = *(const bf16x8*)(smem + row * 132 + (cq << 3));
      *(bf16x8*)(Yb + (yrow0g + (p << 6) + row) * 1024 + col0 + (cq << 3)) = val;
    }
    __syncthreads();
  }
}

// ------- LN2: out = LN((X1h+X1l) + s*(Y + b2); lng,lnb) -- fp32 out -------
__global__ __launch_bounds__(256) void k_ln2b(const u16* __restrict__ Yb,
                                              const u16* __restrict__ X1h, const u16* __restrict__ X1l,
                                              const float* __restrict__ b2a, const float* __restrict__ b2b,
                                              const float* __restrict__ sa, const float* __restrict__ sbp,
                                              const float* __restrict__ ga, const float* __restrict__ gb,
                                              const float* __restrict__ ba, const float* __restrict__ bbp,
                                              float* __restrict__ out) {
  __shared__ float sb[8];
  int row = blockIdx.x; int tid = threadIdx.x;
  int n = row & 4095; int e = n >> 11;
  const float* b2 = e ? b2b : b2a;
  const float* lg = e ? gb : ga;
  const float* lb = e ? bbp : ba;
  float s = e ? sbp[0] : sa[0];
  int c = tid << 2;
  ushort4 yv = *(const ushort4*)(Yb + (size_t)row * 1024 + c);
  ushort4 hv = *(const ushort4*)(X1h + (size_t)row * 1024 + c);
  ushort4 lv = *(const ushort4*)(X1l + (size_t)row * 1024 + c);
  float4 b2v = *(const float4*)(b2 + c);
  float x0 = bf2f(hv.x) + bf2f(lv.x);
  float x1 = bf2f(hv.y) + bf2f(lv.y);
  float x2 = bf2f(hv.z) + bf2f(lv.z);
  float x3 = bf2f(hv.w) + bf2f(lv.w);
  float t0 = x0 + s * (bf2f(yv.x) + b2v.x);
  float t1 = x1 + s * (bf2f(yv.y) + b2v.y);
  float t2 = x2 + s * (bf2f(yv.z) + b2v.z);
  float t3 = x3 + s * (bf2f(yv.w) + b2v.w);
  float mu = blk_sum(t0 + t1 + t2 + t3, sb, tid) * (1.0f / 1024.0f);
  float d0 = t0 - mu, d1 = t1 - mu, d2 = t2 - mu, d3 = t3 - mu;
  float var = blk_sum(d0 * d0 + d1 * d1 + d2 * d2 + d3 * d3, sb, tid) * (1.0f / 1024.0f);
  float rs = 1.0f / sqrtf(var + 1e-5f);
  float4 gv = *(const float4*)(lg + c);
  float4 bv = *(const float4*)(lb + c);
  float4 o;
  o.x = d0 * rs * gv.x + bv.x;
  o.y = d1 * rs * gv.y + bv.y;
  o.z = d2 * rs * gv.z + bv.z;
  o.w = d3 * rs * gv.w + bv.w;
  *(float4*)(out + (size_t)row * 1024 + c) = o;
}

extern "C" void kernel_launch(void* const* d_in, const int* in_sizes, int n_in,
                              void* d_out, int out_size, void* d_ws, size_t ws_size,
                              hipStream_t stream) {
  (void)out_size; (void)ws_size;
  static const int SIG[18] = {16777216, 4096, 1024, 1024,
                              4194304, 4096, 4194304, 1024, 1, 1024, 1024,
                              4194304, 4096, 4194304, 1024, 1, 1024, 1024};
  const void* P[18];
  bool exact = (n_in >= 18);
  if (exact) {
    for (int i = 0; i < 18; i++) {
      if (in_sizes[i] != SIG[i]) { exact = false; break; }
    }
  }
  if (exact) {
    for (int i = 0; i < 18; i++) P[i] = d_in[i];
  } else {
    bool used[64] = {false};
    int cap = (n_in < 64) ? n_in : 64;
    for (int r = 0; r < 18; r++) {
      int found = -1;
      for (int j = 0; j < cap; j++) {
        if (!used[j] && in_sizes[j] == SIG[r]) { found = j; break; }
      }
      if (found >= 0) { used[found] = true; P[r] = d_in[found]; }
      else            { P[r] = d_in[(r < n_in) ? r : 0]; }
    }
  }
  const float* x     = (const float*)P[0];
  const float* wv    = (const float*)P[1];
  const float* ng    = (const float*)P[2];
  const float* nb    = (const float*)P[3];
  const float* w1_0  = (const float*)P[4];
  const float* b1_0  = (const float*)P[5];
  const float* w2_0  = (const float*)P[6];
  const float* b2_0  = (const float*)P[7];
  const float* s_0   = (const float*)P[8];
  const float* lng_0 = (const float*)P[9];
  const float* lnb_0 = (const float*)P[10];
  const float* w1_1  = (const float*)P[11];
  const float* b1_1  = (const float*)P[12];
  const float* w2_1  = (const float*)P[13];
  const float* b2_1  = (const float*)P[14];
  const float* s_1   = (const float*)P[15];
  const float* lng_1 = (const float*)P[16];
  const float* lnb_1 = (const float*)P[17];

  char* ws = (char*)d_ws;
  u16* W1h = (u16*)(ws + 0);           // 16 MB: [2 experts][4096][1024] bf16
  u16* W2h = (u16*)(ws + 16777216);    // 16 MB: [2 experts][1024][4096] bf16
  u16* Xth = (u16*)(ws + 33554432);    // 32 MB [4][1024][4096]  (dead after conv -> X1h)
  u16* X1h = Xth;
  u16* X1l = (u16*)(ws + 67108864);    // 32 MB [16384][1024]
  float* U = (float*)(ws + 100663296); // 64 MB fp32 conv out (dead after LN1)
  u16* Hch = (u16*)(ws + 100663296);   // 64 MB [8192][4096] bf16 (overlays U)
  u16* Yb  = (u16*)(ws + 167772160);   // 32 MB [16384][1024]
  u16* wrh8 = (u16*)(ws + 201326592);  // 8*4352*2 = 69632 B

  k_wsplit<<<136, 256, 0, stream>>>(wv, wrh8);
  k_tsplit<<<4096, 256, 0, stream>>>(x, Xth);
  k_split<<<4096, 256, 0, stream>>>(w1_0, W1h);
  k_split<<<4096, 256, 0, stream>>>(w1_1, W1h + 4194304);
  k_split<<<4096, 256, 0, stream>>>(w2_0, W2h);
  k_split<<<4096, 256, 0, stream>>>(w2_1, W2h + 4194304);
  k_convm<<<1024, 256, 0, stream>>>(Xth, wrh8, x, U);
  k_ln1b<<<16384, 256, 0, stream>>>(U, ng, nb, X1h, X1l);
  for (int e = 0; e < 2; e++) {
    k_ffn1m<<<2048, 256, 0, stream>>>(X1h, W1h, b1_0, b1_1, Hch, e);
    k_ffn2m<<<512, 256, 0, stream>>>(Hch, W2h, Yb, e);
  }
  k_ln2b<<<16384, 256, 0, stream>>>(Yb, X1h, X1l, b2_0, b2_1, s_0, s_1,
                                    lng_0, lng_1, lnb_0, lnb_1, (float*)d_out);
}